// Round 1
// 1011.707 us; speedup vs baseline: 1.0588x; 1.0588x over previous
//
#include <hip/hip_runtime.h>
#include <math.h>

#define DI __device__ __forceinline__

// ---- problem constants ----
#define BB 32
#define SEQ 512
#define KF 101
#define EE 128
#define HH 8
#define EHH 1024
#define LL 3
#define ADIM 200
#define NATOM 119
#define NTOK (BB*SEQ)   // 16384
#define CB 8            // batches per chunk
#define NCHUNK (BB/CB)  // 4
#define CTOK (CB*SEQ)   // 4096 tokens per chunk

// R15: attention softmax expf -> __expf (20 exp/thread/kt was ~5x the MFMA
// issue cost); V produced pre-transposed by QKV GEMM (EPI7 router into
// qkc[tok][h*256+r] + vT[h*128+d][tok]) killing the 32x ds_write_b16
// scatter in attn; FFN epilogue absorbs mish+resid+dual-LN (EPI6) removing
// ln_dual + out2; fast algebraic mish (1 __expf instead of expf+log1p+tanh).

typedef unsigned short u16;
typedef __attribute__((ext_vector_type(8))) short bf16x8;
typedef __attribute__((ext_vector_type(4))) float f32x4;

DI float bf2f(u16 s){ union{unsigned int u; float f;} x; x.u = ((unsigned int)s)<<16; return x.f; }
DI u16 f2bf(float f){
  union{float f; unsigned int u;} x; x.f = f;
  unsigned int u = x.u;
  u += 0x7fffu + ((u>>16)&1u);           // RNE
  return (u16)(u>>16);
}

// =================== sentinel ===================
__global__ void sentinel_k(float* out, float v, int n){
  int i = blockIdx.x*64 + threadIdx.x;
  if (i < n) out[i] = v;
}

// =================== atom embedding precompute ===================
__global__ __launch_bounds__(128) void atomemb_k(
    const float* __restrict__ atom_table, const float* __restrict__ comp_W,
    const float* __restrict__ comp_b, const float* __restrict__ pdd_b,
    float* __restrict__ atom_emb)
{
  const int a = blockIdx.x;      // 0..NATOM-1
  const int e = threadIdx.x;
  __shared__ float sAtom[ADIM];
  for (int d=e; d<ADIM; d+=128) sAtom[d] = atom_table[a*ADIM+d];
  __syncthreads();
  float acc = comp_b[e] + pdd_b[e];
  #pragma unroll 4
  for (int d=0; d<ADIM; d++) acc = fmaf(sAtom[d], comp_W[d*EE+e], acc);
  atom_emb[a*EE+e] = acc;
}

// =================== embed: x = atom_emb[idx] + str[1:]@pdd_W ===================
__global__ __launch_bounds__(128) void embed_k(
    const float* __restrict__ str_fea, const int* __restrict__ comp_fea,
    const float* __restrict__ atom_emb, const float* __restrict__ pdd_W,
    float* __restrict__ x, float* __restrict__ x_init, float* __restrict__ w)
{
  const int t = blockIdx.x;
  const int e = threadIdx.x;
  __shared__ float sStr[104];
  if (e < KF) sStr[e] = str_fea[(size_t)t*KF+e];
  __syncthreads();
  const int idx = comp_fea[t];
  float a0 = atom_emb[idx*EE+e], a1 = 0.f, a2 = 0.f, a3 = 0.f;
  #pragma unroll
  for (int j=0; j<100; j+=4){
    a0 = fmaf(sStr[1+j],   pdd_W[(j  )*EE+e], a0);
    a1 = fmaf(sStr[2+j],   pdd_W[(j+1)*EE+e], a1);
    a2 = fmaf(sStr[3+j],   pdd_W[(j+2)*EE+e], a2);
    a3 = fmaf(sStr[4+j],   pdd_W[(j+3)*EE+e], a3);
  }
  const float acc = (a0+a1)+(a2+a3);
  x[(size_t)t*EE+e] = acc;
  x_init[(size_t)t*EE+e] = acc;
  if (e==0) w[t] = sStr[0];
}

// =================== layernorm: wave per token ===================
template<bool OBF>
__global__ __launch_bounds__(256) void ln_k(
    const float* __restrict__ in, const float* __restrict__ add,
    const float* __restrict__ g, const float* __restrict__ bta,
    void* __restrict__ outv)
{
  const int wv = threadIdx.x >> 6, lane = threadIdx.x & 63;
  const int t = blockIdx.x*4 + wv;
  float2 v = ((const float2*)(in + (size_t)t*EE))[lane];
  if (add){
    const float2 a = ((const float2*)(add + (size_t)t*EE))[lane];
    v.x += a.x; v.y += a.y;
  }
  float s = v.x + v.y;
  #pragma unroll
  for (int off=32; off; off>>=1) s += __shfl_xor(s, off);
  const float mean = s*(1.0f/128.0f);
  const float d0 = v.x-mean, d1 = v.y-mean;
  float q = d0*d0 + d1*d1;
  #pragma unroll
  for (int off=32; off; off>>=1) q += __shfl_xor(q, off);
  const float rstd = rsqrtf(q*(1.0f/128.0f) + 1e-5f);
  const float2 gg = ((const float2*)g)[lane];
  const float2 bb = ((const float2*)bta)[lane];
  const float r0 = d0*rstd*gg.x + bb.x;
  const float r1 = d1*rstd*gg.y + bb.y;
  if constexpr (OBF){
    u16* o = (u16*)outv + (size_t)t*EE + lane*2;
    o[0] = f2bf(r0); o[1] = f2bf(r1);
  } else {
    float2* o = (float2*)((float*)outv + (size_t)t*EE);
    o[lane] = make_float2(r0, r1);
  }
}

// =================== coalesced convert: f32 -> bf16 ===================
__global__ __launch_bounds__(256) void cconv_k(
    const float* __restrict__ W, u16* __restrict__ Wb, int n)
{
  const int i = blockIdx.x*256 + threadIdx.x;
  if (i < n) Wb[i] = f2bf(W[i]);
}

// =================== LDS-tiled transpose convert, layer-batched via z ===================
__global__ __launch_bounds__(256) void tconvT_k(
    const float* __restrict__ W, u16* __restrict__ WT, int Kk, int Nn,
    size_t sW, size_t sWT)
{
  W  += (size_t)blockIdx.z*sW;
  WT += (size_t)blockIdx.z*sWT;
  __shared__ u16 tile[32][33];
  const int n0 = blockIdx.x*32, k0 = blockIdx.y*32;
  const int lr = threadIdx.x >> 5, lc = threadIdx.x & 31;
  #pragma unroll
  for (int i=0;i<4;i++){
    const int k = k0 + lr + i*8;
    tile[lr+i*8][lc] = f2bf(W[(size_t)k*Nn + n0 + lc]);
  }
  __syncthreads();
  #pragma unroll
  for (int i=0;i<4;i++){
    const int n = n0 + lr + i*8;
    WT[(size_t)n*Kk + k0 + lc] = tile[lc][lr+i*8];
  }
}

// =================== qkv weight: transpose+convert+REORDER ===================
// dst n-order: n<2048 -> (h=n>>8, r=n&255) src col h*384+r  (Q then K)
//              n>=2048 -> (m=n-2048, h=m>>7, d=m&127) src col h*384+256+d (V)
// 32-wide tiles never cross a head/region boundary (256%32==0, 128%32==0).
__global__ __launch_bounds__(256) void qkvT_k(
    const float* __restrict__ W, u16* __restrict__ WT)
{
  const int l = blockIdx.z;
  W  += (size_t)l*EE*3*EHH;
  WT += (size_t)l*3*EHH*EE;
  __shared__ u16 tile[32][33];
  const int n0 = blockIdx.x*32, k0 = blockIdx.y*32;
  int c0;
  if (n0 < 2048) c0 = (n0>>8)*384 + (n0&255);
  else { const int m0 = n0-2048; c0 = (m0>>7)*384 + 256 + (m0&127); }
  const int lr = threadIdx.x >> 5, lc = threadIdx.x & 31;
  #pragma unroll
  for (int i=0;i<4;i++){
    const int k = k0 + lr + i*8;
    tile[lr+i*8][lc] = f2bf(W[(size_t)k*(3*EHH) + c0 + lc]);
  }
  __syncthreads();
  #pragma unroll
  for (int i=0;i<4;i++){
    const int n = n0 + lr + i*8;
    WT[(size_t)n*EE + k0 + lc] = tile[lc][lr+i*8];
  }
}

// =================== qkv bias reorder (same n-mapping) ===================
__global__ __launch_bounds__(256) void biasre_k(
    const float* __restrict__ b, float* __restrict__ rb)
{
  const int l = blockIdx.y;
  const int n = blockIdx.x*256 + threadIdx.x;   // < 3072
  int c;
  if (n < 2048) c = (n>>8)*384 + (n&255);
  else { const int m = n-2048; c = (m>>7)*384 + 256 + (m&127); }
  rb[(size_t)l*3*EHH + n] = b[(size_t)l*3*EHH + c];
}

// =================== MFMA bf16 GEMM (layer-batched via z strides) ===================
// A: M x Kk bf16 row-major. BT: Nn x Kk bf16 (pre-transposed B).
// EPI 0: store bf16; 2: f32 +resid; 3: f32 mish; 4: bf16 transposed store
// (no bias); EPI 5 (BM<=64, BN=Nn=128): v=acc+bias+resid -> C f32 AND
// row-LN(v)*lng+lnb -> C2 bf16.
// EPI 6 (BM<=64, BN=Nn=128): t = resid + mish(acc+bias); x=LN1(t)->C f32;
// xn=LN2(x)->C2 bf16 (dual row-LN, fuses old ln_dual).
// EPI 7 (QKV router): col<2048 -> ((u16*)C)[row*2048+col];
//                     col>=2048 -> ((u16*)C2)[(col-2048)*Mdim+row] (V^T).
template<int EPI, int BM, int BN>
__global__ __launch_bounds__(256) void mgemm_k(
    const u16* __restrict__ A, const u16* __restrict__ BT,
    const float* __restrict__ bias, const float* __restrict__ resid,
    void* __restrict__ Cv, int Nn, int Kk, int Mdim,
    void* __restrict__ C2, const float* __restrict__ lng,
    const float* __restrict__ lnb, const float* __restrict__ lng2,
    const float* __restrict__ lnb2,
    size_t sA, size_t sBT, size_t sCb)
{
  const int lz = blockIdx.z;
  A  += (size_t)lz*sA;
  BT += (size_t)lz*sBT;
  void* C = (void*)((char*)Cv + (size_t)lz*sCb);

  constexpr int BK  = 64;
  constexpr int LDK = BK + 8;
  __shared__ u16 As[BM*LDK];
  __shared__ u16 Bs[BN*LDK];
  const int tid = threadIdx.x;
  const int m0 = blockIdx.y*BM, n0 = blockIdx.x*BN;
  constexpr int WMN = (BM>=128)?2:1;
  constexpr int WNN = 4/WMN;
  constexpr int WM = BM/WMN;
  constexpr int WN = BN/WNN;
  constexpr int FM = WM/16, FN = WN/16;
  const int wv = tid>>6, lane = tid&63;
  const int wm = (wv/WNN)*WM;
  const int wn = (wv%WNN)*WN;
  const int lm = lane&15, lq = lane>>4;

  f32x4 acc[FM][FN];
  #pragma unroll
  for (int i=0;i<FM;i++)
    #pragma unroll
    for (int j=0;j<FN;j++) acc[i][j] = (f32x4){0.f,0.f,0.f,0.f};

  constexpr int ACH = BM*BK/8;
  constexpr int BCH = BN*BK/8;

  for (int k0=0; k0<Kk; k0+=BK){
    #pragma unroll
    for (int c = tid; c < ACH; c += 256){
      const int r = c/(BK/8), kg = c - r*(BK/8);
      const float4 v = *(const float4*)(A + (size_t)(m0+r)*Kk + k0 + kg*8);
      *(float4*)&As[r*LDK + kg*8] = v;
    }
    #pragma unroll
    for (int c = tid; c < BCH; c += 256){
      const int r = c/(BK/8), kg = c - r*(BK/8);
      const float4 v = *(const float4*)(BT + (size_t)(n0+r)*Kk + k0 + kg*8);
      *(float4*)&Bs[r*LDK + kg*8] = v;
    }
    __syncthreads();
    #pragma unroll
    for (int kk=0; kk<BK/32; kk++){
      bf16x8 af[FM], bfr[FN];
      #pragma unroll
      for (int i=0;i<FM;i++)
        af[i] = *(const bf16x8*)&As[(wm + i*16 + lm)*LDK + kk*32 + lq*8];
      #pragma unroll
      for (int j=0;j<FN;j++)
        bfr[j] = *(const bf16x8*)&Bs[(wn + j*16 + lm)*LDK + kk*32 + lq*8];
      #pragma unroll
      for (int i=0;i<FM;i++)
        #pragma unroll
        for (int j=0;j<FN;j++)
          acc[i][j] = __builtin_amdgcn_mfma_f32_16x16x32_bf16(af[i], bfr[j], acc[i][j], 0, 0, 0);
    }
    __syncthreads();
  }
  if constexpr (EPI==5){
    // fused proj + residual + row-LN (wm==0, BN=Nn=128)
    float vout[FM][FN][4];
    float ps[FM][4], qs[FM][4];
    #pragma unroll
    for (int i=0;i<FM;i++)
      #pragma unroll
      for (int r=0;r<4;r++){ ps[i][r]=0.f; qs[i][r]=0.f; }
    #pragma unroll
    for (int i=0;i<FM;i++){
      #pragma unroll
      for (int j=0;j<FN;j++){
        const int col = n0 + wn + j*16 + lm;
        const float bv = bias[col];
        #pragma unroll
        for (int r=0;r<4;r++){
          const int row = m0 + i*16 + lq*4 + r;
          const size_t gi = (size_t)row*Nn + col;
          const float v = acc[i][j][r] + bv + resid[gi];
          ((float*)C)[gi] = v;
          vout[i][j][r] = v;
          ps[i][r] += v; qs[i][r] += v*v;
        }
      }
    }
    float* sred = (float*)As;
    #pragma unroll
    for (int i=0;i<FM;i++)
      #pragma unroll
      for (int r=0;r<4;r++){
        float s = ps[i][r], q = qs[i][r];
        s += __shfl_xor(s,1); s += __shfl_xor(s,2); s += __shfl_xor(s,4); s += __shfl_xor(s,8);
        q += __shfl_xor(q,1); q += __shfl_xor(q,2); q += __shfl_xor(q,4); q += __shfl_xor(q,8);
        if (lm==0){
          const int row = i*16 + lq*4 + r;
          sred[row*4 + wv] = s;
          sred[BM*4 + row*4 + wv] = q;
        }
      }
    __syncthreads();
    #pragma unroll
    for (int i=0;i<FM;i++)
      #pragma unroll
      for (int r=0;r<4;r++){
        const int row = i*16 + lq*4 + r;
        const float s = sred[row*4+0]+sred[row*4+1]+sred[row*4+2]+sred[row*4+3];
        const float q = sred[BM*4+row*4+0]+sred[BM*4+row*4+1]+sred[BM*4+row*4+2]+sred[BM*4+row*4+3];
        const float mean = s*(1.0f/128.0f);
        const float var  = q*(1.0f/128.0f) - mean*mean;
        const float rstd = rsqrtf(var + 1e-5f);
        #pragma unroll
        for (int j=0;j<FN;j++){
          const int col = n0 + wn + j*16 + lm;
          const float xnv = (vout[i][j][r]-mean)*rstd*lng[col] + lnb[col];
          ((u16*)C2)[(size_t)(m0+row)*Nn + col] = f2bf(xnv);
        }
      }
  } else if constexpr (EPI==6){
    // fused ffn: t = resid + mish(acc+bias); x = LN1(t) -> C f32;
    // xn = LN2(x) -> C2 bf16.  (wm==0, BN=Nn=128)
    float tv[FM][FN][4];
    float ps[FM][4], qs[FM][4];
    #pragma unroll
    for (int i=0;i<FM;i++)
      #pragma unroll
      for (int r=0;r<4;r++){ ps[i][r]=0.f; qs[i][r]=0.f; }
    #pragma unroll
    for (int i=0;i<FM;i++){
      #pragma unroll
      for (int j=0;j<FN;j++){
        const int col = n0 + wn + j*16 + lm;
        const float bv = bias[col];
        #pragma unroll
        for (int r=0;r<4;r++){
          const int row = m0 + i*16 + lq*4 + r;
          const size_t gi = (size_t)row*Nn + col;
          const float v = acc[i][j][r] + bv;
          // mish(v) = v*(E^2+2E)/(E^2+2E+2), E=e^v; exact enough, 1 exp
          const float E = __expf(v);
          const float uu = E*E + 2.f*E;
          const float mi = (v > 20.f) ? v : v*(uu/(uu+2.f));
          const float t = resid[gi] + mi;
          tv[i][j][r] = t;
          ps[i][r] += t; qs[i][r] += t*t;
        }
      }
    }
    float* sred = (float*)As;
    #pragma unroll
    for (int i=0;i<FM;i++)
      #pragma unroll
      for (int r=0;r<4;r++){
        float s = ps[i][r], q = qs[i][r];
        s += __shfl_xor(s,1); s += __shfl_xor(s,2); s += __shfl_xor(s,4); s += __shfl_xor(s,8);
        q += __shfl_xor(q,1); q += __shfl_xor(q,2); q += __shfl_xor(q,4); q += __shfl_xor(q,8);
        if (lm==0){
          const int row = i*16 + lq*4 + r;
          sred[row*4 + wv] = s;
          sred[BM*4 + row*4 + wv] = q;
        }
      }
    __syncthreads();
    float xv[FM][FN][4];
    float ps2[FM][4], qs2[FM][4];
    #pragma unroll
    for (int i=0;i<FM;i++)
      #pragma unroll
      for (int r=0;r<4;r++){
        const int row = i*16 + lq*4 + r;
        const float s = sred[row*4+0]+sred[row*4+1]+sred[row*4+2]+sred[row*4+3];
        const float q = sred[BM*4+row*4+0]+sred[BM*4+row*4+1]+sred[BM*4+row*4+2]+sred[BM*4+row*4+3];
        const float mean = s*(1.0f/128.0f);
        const float var  = q*(1.0f/128.0f) - mean*mean;
        const float rstd = rsqrtf(var + 1e-5f);
        float s2 = 0.f, q2 = 0.f;
        #pragma unroll
        for (int j=0;j<FN;j++){
          const int col = n0 + wn + j*16 + lm;
          const float xnv = (tv[i][j][r]-mean)*rstd*lng[col] + lnb[col];
          ((float*)C)[(size_t)(m0+row)*Nn + col] = xnv;
          xv[i][j][r] = xnv;
          s2 += xnv; q2 += xnv*xnv;
        }
        ps2[i][r] = s2; qs2[i][r] = q2;
      }
    __syncthreads();    // round-1 reads done before sred reuse
    #pragma unroll
    for (int i=0;i<FM;i++)
      #pragma unroll
      for (int r=0;r<4;r++){
        float s = ps2[i][r], q = qs2[i][r];
        s += __shfl_xor(s,1); s += __shfl_xor(s,2); s += __shfl_xor(s,4); s += __shfl_xor(s,8);
        q += __shfl_xor(q,1); q += __shfl_xor(q,2); q += __shfl_xor(q,4); q += __shfl_xor(q,8);
        if (lm==0){
          const int row = i*16 + lq*4 + r;
          sred[row*4 + wv] = s;
          sred[BM*4 + row*4 + wv] = q;
        }
      }
    __syncthreads();
    #pragma unroll
    for (int i=0;i<FM;i++)
      #pragma unroll
      for (int r=0;r<4;r++){
        const int row = i*16 + lq*4 + r;
        const float s = sred[row*4+0]+sred[row*4+1]+sred[row*4+2]+sred[row*4+3];
        const float q = sred[BM*4+row*4+0]+sred[BM*4+row*4+1]+sred[BM*4+row*4+2]+sred[BM*4+row*4+3];
        const float mean = s*(1.0f/128.0f);
        const float var  = q*(1.0f/128.0f) - mean*mean;
        const float rstd = rsqrtf(var + 1e-5f);
        #pragma unroll
        for (int j=0;j<FN;j++){
          const int col = n0 + wn + j*16 + lm;
          const float xnv = (xv[i][j][r]-mean)*rstd*lng2[col] + lnb2[col];
          ((u16*)C2)[(size_t)(m0+row)*Nn + col] = f2bf(xnv);
        }
      }
  } else {
    #pragma unroll
    for (int i=0;i<FM;i++){
      #pragma unroll
      for (int j=0;j<FN;j++){
        const int col = n0 + wn + j*16 + lm;
        const float bv = (EPI==4) ? 0.f : bias[col];
        #pragma unroll
        for (int r=0;r<4;r++){
          const int row = m0 + wm + i*16 + lq*4 + r;
          float v = acc[i][j][r] + bv;
          if constexpr (EPI==7){
            if (col < 2048) ((u16*)C)[(size_t)row*2048 + col] = f2bf(v);
            else            ((u16*)C2)[(size_t)(col-2048)*Mdim + row] = f2bf(v);
          } else if constexpr (EPI==4){
            ((u16*)C)[(size_t)col*Mdim + row] = f2bf(v);
          } else {
            const size_t gi = (size_t)row*Nn + col;
            if constexpr (EPI==0)      ((u16*)C)[gi] = f2bf(v);
            else if constexpr (EPI==2) ((float*)C)[gi] = v + resid[gi];
            else { const float sp=(v>20.f)?v:log1pf(expf(v)); ((float*)C)[gi]=v*tanhf(sp); }
          }
        }
      }
    }
  }
}

// =================== fb = o_b@out_W + out_b (layer-batched) ===================
__global__ __launch_bounds__(128) void fuse_b_k(
    const float* __restrict__ ob, const float* __restrict__ outW,
    const float* __restrict__ outb, float* __restrict__ fb)
{
  const int ly = blockIdx.x;
  ob   += (size_t)ly*EHH;
  outW += (size_t)ly*EHH*EE;
  outb += (size_t)ly*EE;
  fb   += (size_t)ly*EE;
  const int n = threadIdx.x;
  float acc = outb[n];
  for (int k2=0;k2<EHH;k2++) acc = fmaf(ob[k2], outW[(size_t)k2*EE+n], acc);
  fb[n] = acc;
}

// =================== MFMA flash attention (XCD-local grid: bl,h,qt) ===================
// qkc: [tok][h*256 + (q:0..127 | k:128..255)] bf16, tok chunk-local.
// vTc: [h*128+d][tok] bf16 (pre-transposed V), tok chunk-local.
__global__ __launch_bounds__(256) void attn_mf_k(
    const u16* __restrict__ qkc, const u16* __restrict__ vTc,
    const float* __restrict__ w, u16* __restrict__ vals_c, int b0)
{
  const int bl = blockIdx.x;   // id%8 = bl -> one XCD per batch
  const int h  = blockIdx.y;
  const int qt = blockIdx.z;
  const int tid = threadIdx.x;
  const int wv = tid>>6, lane = tid&63;
  const int lm = lane&15, lq = lane>>4;

  __shared__ u16 Qs[64][136];
  __shared__ u16 Ks[64][136];
  __shared__ u16 Vts[128][72];
  __shared__ u16 Ps[64][72];
  __shared__ float wt[64], qwt[64];

  const size_t rs = 2048;
  const u16* qk = qkc + (size_t)bl*SEQ*rs + (size_t)h*256;
  const u16* vb = vTc + (size_t)h*128*CTOK + (size_t)bl*SEQ;
  const int q0 = qt*64;

  #pragma unroll
  for (int it=0; it<4; it++){
    const int fi = it*256 + tid;
    const int r = fi >> 4, g = fi & 15;
    *(float4*)&Qs[r][g*8] = *(const float4*)(qk + (size_t)(q0+r)*rs + g*8);
  }
  if (tid < 64) qwt[tid] = w[(b0+bl)*SEQ + q0 + tid];
  __syncthreads();

  float kq[4];
  #pragma unroll
  for (int r=0;r<4;r++) kq[r] = qwt[wv*16 + lq*4 + r];

  f32x4 oacc[8];
  #pragma unroll
  for (int j=0;j<8;j++) oacc[j] = (f32x4){0.f,0.f,0.f,0.f};
  float mrow[4], lrow[4];
  #pragma unroll
  for (int r=0;r<4;r++){ mrow[r]=-INFINITY; lrow[r]=0.f; }
  const float scale = 0.08838834764831845f;  // 1/sqrt(128)

  for (int kt=0; kt<8; kt++){
    __syncthreads();
    #pragma unroll
    for (int it=0; it<4; it++){
      const int fi = it*256 + tid;
      const int r = fi >> 4, g = fi & 15;
      *(float4*)&Ks[r][g*8] = *(const float4*)(qk + (size_t)(kt*64+r)*rs + 128 + g*8);
    }
    #pragma unroll
    for (int it=0; it<4; it++){
      const int fi = it*256 + tid;
      const int d = fi >> 3, g = fi & 7;
      *(float4*)&Vts[d][g*8] = *(const float4*)(vb + (size_t)d*CTOK + kt*64 + g*8);
    }
    if (tid < 64) wt[tid] = w[(b0+bl)*SEQ + kt*64 + tid];
    __syncthreads();

    f32x4 sacc[4];
    #pragma unroll
    for (int j=0;j<4;j++) sacc[j] = (f32x4){0.f,0.f,0.f,0.f};
    #pragma unroll
    for (int kk=0; kk<4; kk++){
      const bf16x8 af = *(const bf16x8*)&Qs[wv*16+lm][kk*32+lq*8];
      #pragma unroll
      for (int j=0;j<4;j++){
        const bf16x8 bf = *(const bf16x8*)&Ks[j*16+lm][kk*32+lq*8];
        sacc[j] = __builtin_amdgcn_mfma_f32_16x16x32_bf16(af, bf, sacc[j], 0, 0, 0);
      }
    }
    float wkj[4], s[4][4];
    #pragma unroll
    for (int j=0;j<4;j++) wkj[j] = wt[j*16+lm];
    #pragma unroll
    for (int j=0;j<4;j++)
      #pragma unroll
      for (int r=0;r<4;r++){
        const bool keep = (kq[r] > 0.f) && (wkj[j] > 0.f);
        s[j][r] = keep ? sacc[j][r]*scale : -9.0e15f;
      }
    float alpha[4];
    #pragma unroll
    for (int r=0;r<4;r++){
      float rm = fmaxf(fmaxf(s[0][r], s[1][r]), fmaxf(s[2][r], s[3][r]));
      rm = fmaxf(rm, __shfl_xor(rm, 1));
      rm = fmaxf(rm, __shfl_xor(rm, 2));
      rm = fmaxf(rm, __shfl_xor(rm, 4));
      rm = fmaxf(rm, __shfl_xor(rm, 8));
      const float newm = fmaxf(mrow[r], rm);
      alpha[r] = __expf(mrow[r] - newm);
      float ls = 0.f;
      #pragma unroll
      for (int j=0;j<4;j++){
        const float pv = wkj[j]*__expf(s[j][r]-newm);
        s[j][r] = pv; ls += pv;
      }
      ls += __shfl_xor(ls, 1);
      ls += __shfl_xor(ls, 2);
      ls += __shfl_xor(ls, 4);
      ls += __shfl_xor(ls, 8);
      lrow[r] = lrow[r]*alpha[r] + ls;
      mrow[r] = newm;
    }
    #pragma unroll
    for (int j=0;j<4;j++)
      #pragma unroll
      for (int r=0;r<4;r++)
        Ps[wv*16 + lq*4 + r][j*16+lm] = f2bf(s[j][r]);
    #pragma unroll
    for (int j=0;j<8;j++)
      #pragma unroll
      for (int r=0;r<4;r++) oacc[j][r] *= alpha[r];
    __syncthreads();

    #pragma unroll
    for (int kk=0; kk<2; kk++){
      const bf16x8 pf = *(const bf16x8*)&Ps[wv*16+lm][kk*32+lq*8];
      #pragma unroll
      for (int j=0;j<8;j++){
        const bf16x8 vf = *(const bf16x8*)&Vts[j*16+lm][kk*32+lq*8];
        oacc[j] = __builtin_amdgcn_mfma_f32_16x16x32_bf16(pf, vf, oacc[j], 0, 0, 0);
      }
    }
  }
  #pragma unroll
  for (int r=0;r<4;r++){
    const float inv = 1.0f / lrow[r];
    u16* orow = vals_c + ((size_t)(bl*SEQ + q0 + wv*16 + lq*4 + r))*EHH + h*EE;
    #pragma unroll
    for (int j=0;j<8;j++) orow[j*16+lm] = f2bf(oacc[j][r]*inv);
  }
}

// =================== pool phase 1: partial weighted sums ===================
__global__ __launch_bounds__(128) void pool1_k(
    const float* __restrict__ x, const float* __restrict__ x_init,
    const float* __restrict__ w, float* __restrict__ part)
{
  const int bc = blockIdx.x;          // b*4 + c
  const int b = bc >> 2, c = bc & 3;
  const int e = threadIdx.x;
  float acc = 0.f;
  const int n0 = c*128;
  for (int n=0;n<128;n++){
    const int tok = b*SEQ + n0 + n;
    const size_t idx = (size_t)tok*EE + e;
    acc = fmaf(w[tok], x[idx]+x_init[idx], acc);
  }
  part[(size_t)bc*EE + e] = acc;
}

// =================== pool phase 2: sum parts + LN + head ===================
__global__ __launch_bounds__(128) void pool2_k(
    const float* __restrict__ part, const float* __restrict__ g2,
    const float* __restrict__ b2, const float* __restrict__ head_W,
    const float* __restrict__ head_b, float* __restrict__ out)
{
  const int b = blockIdx.x;
  const int e = threadIdx.x;
  __shared__ float red[128];
  float acc = part[(size_t)(b*4+0)*EE+e] + part[(size_t)(b*4+1)*EE+e]
            + part[(size_t)(b*4+2)*EE+e] + part[(size_t)(b*4+3)*EE+e];
  red[e]=acc; __syncthreads();
  for (int s=64;s>0;s>>=1){ if(e<s) red[e]+=red[e+s]; __syncthreads(); }
  const float mean = red[0]*(1.0f/128.0f);
  __syncthreads();
  const float d = acc-mean;
  red[e]=d*d; __syncthreads();
  for (int s=64;s>0;s>>=1){ if(e<s) red[e]+=red[e+s]; __syncthreads(); }
  const float var = red[0]*(1.0f/128.0f);
  const float p = d*rsqrtf(var+1e-5f)*g2[e]+b2[e];
  __syncthreads();
  red[e] = p*head_W[e]; __syncthreads();
  for (int s=64;s>0;s>>=1){ if(e<s) red[e]+=red[e+s]; __syncthreads(); }
  if (e==0) out[b] = red[0] + head_b[0];
}

// =================== launch ===================
extern "C" void kernel_launch(void* const* d_in, const int* in_sizes, int n_in,
                              void* d_out, int out_size, void* d_ws, size_t ws_size,
                              hipStream_t stream)
{
  const float* str_fea   = (const float*)d_in[0];
  const int*   comp_fea  = (const int*)  d_in[1];
  // d_in[2] cell_fea unused by reference
  const float* atom_table= (const float*)d_in[3];
  const float* comp_W    = (const float*)d_in[4];
  const float* comp_b    = (const float*)d_in[5];
  const float* pdd_W     = (const float*)d_in[6];
  const float* pdd_b     = (const float*)d_in[7];
  const float* enc_ln_g  = (const float*)d_in[8];
  const float* enc_ln_b  = (const float*)d_in[9];
  const float* qkv_W     = (const float*)d_in[10];
  const float* qkv_b     = (const float*)d_in[11];
  const float* o_W       = (const float*)d_in[12];
  const float* o_b       = (const float*)d_in[13];
  const float* out_W     = (const float*)d_in[14];
  const float* out_b     = (const float*)d_in[15];
  const float* ffn_W     = (const float*)d_in[16];
  const float* ffn_b     = (const float*)d_in[17];
  const float* ln2_g     = (const float*)d_in[18];
  const float* ln2_b     = (const float*)d_in[19];
  const float* head_W    = (const float*)d_in[20];
  const float* head_b    = (const float*)d_in[21];
  float* out = (float*)d_out;

  // ---- diagnostic 1: input layout model ----
  bool sizes_ok = (n_in >= 22);
  if (sizes_ok){
    sizes_ok = in_sizes[0]==BB*SEQ*KF && in_sizes[1]==NTOK &&
               in_sizes[3]==NATOM*ADIM && in_sizes[4]==ADIM*EE &&
               in_sizes[10]==LL*EE*3*EHH && in_sizes[12]==LL*EHH*EHH &&
               in_sizes[14]==LL*EHH*EE   && in_sizes[16]==LL*EE*EE &&
               in_sizes[20]==EE;
  }
  if (!sizes_ok){
    sentinel_k<<<(out_size+63)/64,64,0,stream>>>(out, 99999.0f, out_size);
    return;
  }

  // ---- workspace layout (~99 MB; <= 109.7 MB proven) ----
  char* p = (char*)d_ws;
  size_t off = 0;
  auto alloc = [&](size_t bytes)->void*{
    off = (off + 255) & ~(size_t)255;
    void* r = p + off; off += bytes; return r;
  };
  float* w        = (float*)alloc((size_t)NTOK*4);
  float* x        = (float*)alloc((size_t)NTOK*EE*4);
  float* x_init   = (float*)alloc((size_t)NTOK*EE*4);
  u16*   xn_bf    = (u16*)  alloc((size_t)NTOK*EE*2);
  float* out1     = (float*)alloc((size_t)NTOK*EE*4);
  u16*   qkc      = (u16*)  alloc((size_t)CTOK*2048*2);   // 16.8 MB chunk (Q|K)
  u16*   vTc      = (u16*)  alloc((size_t)EHH*CTOK*2);    // 8.4 MB chunk (V^T)
  u16*   vals_bf  = (u16*)  alloc((size_t)NTOK*EHH*2);    // 33.6 MB
  u16*   qkvWT_a  = (u16*)  alloc((size_t)LL*3*EHH*EE*2); // 2.36 MB (reordered)
  float* rqkv_b   = (float*)alloc((size_t)LL*3*EHH*4);    // reordered bias
  u16*   fwT_a    = (u16*)  alloc((size_t)LL*EE*EHH*2);   // 0.79 MB
  u16*   ffnWT_a  = (u16*)  alloc((size_t)LL*EE*EE*2);
  u16*   oWb_a    = (u16*)  alloc((size_t)LL*EHH*EHH*2);  // 6.29 MB
  u16*   outWT_a  = (u16*)  alloc((size_t)LL*EE*EHH*2);
  float* fb_a     = (float*)alloc((size_t)LL*EE*4);
  float* atom_emb = (float*)alloc((size_t)NATOM*EE*4);
  float* part     = (float*)alloc((size_t)BB*4*EE*4);

  // ---- diagnostic 2: workspace size ----
  if (off > ws_size){
    sentinel_k<<<(out_size+63)/64,64,0,stream>>>(out, 12345.0f, out_size);
    return;
  }

  // ---- hoisted weight prep (all layers, batched) ----
  qkvT_k<<<dim3(3*EHH/32, EE/32, LL),256,0,stream>>>(qkv_W, qkvWT_a);
  biasre_k<<<dim3(3*EHH/256, LL),256,0,stream>>>(qkv_b, rqkv_b);
  tconvT_k<<<dim3(EE/32, EE/32, LL),256,0,stream>>>(
      ffn_W, ffnWT_a, EE, EE, (size_t)EE*EE, (size_t)EE*EE);
  cconv_k<<<(LL*EHH*EHH+255)/256,256,0,stream>>>(o_W, oWb_a, LL*EHH*EHH);
  tconvT_k<<<dim3(EE/32, EHH/32, LL),256,0,stream>>>(
      out_W, outWT_a, EHH, EE, (size_t)EHH*EE, (size_t)EE*EHH);
  // fwT = (o_W @ out_W)^T per layer (EPI4 transposed store), grid.z = layers
  mgemm_k<4,32,128><<<dim3(1, EHH/32, LL),256,0,stream>>>(
      oWb_a, outWT_a, nullptr, nullptr, fwT_a, EE, EHH, EHH,
      nullptr, nullptr, nullptr, nullptr, nullptr,
      (size_t)EHH*EHH, (size_t)EE*EHH, (size_t)EE*EHH*2);
  fuse_b_k<<<LL,128,0,stream>>>(o_b, out_W, out_b, fb_a);

  atomemb_k<<<NATOM,128,0,stream>>>(atom_table, comp_W, comp_b, pdd_b, atom_emb);
  embed_k<<<NTOK,128,0,stream>>>(str_fea, comp_fea, atom_emb, pdd_W, x, x_init, w);

  for (int i=0;i<LL;i++){
    const float* gi = enc_ln_g + i*EE;
    const float* bi = enc_ln_b + i*EE;
    if (i==0) ln_k<true><<<NTOK/4,256,0,stream>>>(x, nullptr, gi, bi, xn_bf);
    for (int cb=0; cb<NCHUNK; cb++){
      const int t0 = cb*CTOK;
      const int b0 = cb*CB;
      // QKV with router epilogue: Q|K -> qkc (stride 2048), V -> vTc (transposed)
      mgemm_k<7,128,128><<<dim3(3*EHH/128, CTOK/128),256,0,stream>>>(
          xn_bf + (size_t)t0*EE, qkvWT_a + (size_t)i*3*EHH*EE,
          rqkv_b + (size_t)i*3*EHH, nullptr,
          qkc, 3*EHH, EE, CTOK, vTc, nullptr, nullptr, nullptr, nullptr, 0, 0, 0);
      attn_mf_k<<<dim3(CB, HH, SEQ/64),256,0,stream>>>(
          qkc, vTc, w, vals_bf + (size_t)t0*EHH, b0);
    }
    // proj + resid + fused LN -> out1 (f32) + xn_bf   [BM=32, grid 512]
    mgemm_k<5,32,128><<<dim3(1, NTOK/32),256,0,stream>>>(
        vals_bf, fwT_a + (size_t)i*EE*EHH, fb_a + (size_t)i*EE, x,
        out1, EE, EHH, 0, xn_bf, gi, bi, nullptr, nullptr, 0, 0, 0);
    // ffn + mish + resid(out1) + dual row-LN -> x (f32) + xn_bf (next layer)
    const float* gn = (i<LL-1) ? enc_ln_g + (i+1)*EE : gi;
    const float* bn = (i<LL-1) ? enc_ln_b + (i+1)*EE : bi;
    mgemm_k<6,32,128><<<dim3(1, NTOK/32),256,0,stream>>>(
        xn_bf, ffnWT_a + (size_t)i*EE*EE, ffn_b + (size_t)i*EE, out1,
        x, EE, EE, 0, xn_bf, gi, bi, gn, bn, 0, 0, 0);
  }
  pool1_k<<<BB*4,128,0,stream>>>(x, x_init, w, part);
  pool2_k<<<BB,128,0,stream>>>(part, ln2_g, ln2_b, head_W, head_b, out);
}

// Round 2
// 970.774 us; speedup vs baseline: 1.1035x; 1.0422x over previous
//
#include <hip/hip_runtime.h>
#include <math.h>

#define DI __device__ __forceinline__

// ---- problem constants ----
#define BB 32
#define SEQ 512
#define KF 101
#define EE 128
#define HH 8
#define EHH 1024
#define LL 3
#define ADIM 200
#define NATOM 119
#define NTOK (BB*SEQ)   // 16384
#define CB 8            // batches per chunk
#define NCHUNK (BB/CB)  // 4
#define CTOK (CB*SEQ)   // 4096 tokens per chunk

// R16: launch-count + latency-bound-straggler round. 41 -> 33 dispatches:
// prep merged (5->1), fuse_b parallelized (1024-serial -> 4-way split),
// embed fused with layer-0 LN + LDS-staged pdd_W (kills 840MB L2 re-read),
// proj+ffn+mish+dual-LN fused into projffn_k (out1 buffer + xn round-trip
// eliminated, MFMA order unchanged = bitwise), fwT prep GEMM BK=128,
// pool1+pool2 fused. Attention + QKV router unchanged.

typedef unsigned short u16;
typedef __attribute__((ext_vector_type(8))) short bf16x8;
typedef __attribute__((ext_vector_type(4))) float f32x4;

DI float bf2f(u16 s){ union{unsigned int u; float f;} x; x.u = ((unsigned int)s)<<16; return x.f; }
DI u16 f2bf(float f){
  union{float f; unsigned int u;} x; x.f = f;
  unsigned int u = x.u;
  u += 0x7fffu + ((u>>16)&1u);           // RNE
  return (u16)(u>>16);
}

// =================== sentinel ===================
__global__ void sentinel_k(float* out, float v, int n){
  int i = blockIdx.x*64 + threadIdx.x;
  if (i < n) out[i] = v;
}

// =================== atom embedding precompute ===================
__global__ __launch_bounds__(128) void atomemb_k(
    const float* __restrict__ atom_table, const float* __restrict__ comp_W,
    const float* __restrict__ comp_b, const float* __restrict__ pdd_b,
    float* __restrict__ atom_emb)
{
  const int a = blockIdx.x;      // 0..NATOM-1
  const int e = threadIdx.x;
  __shared__ float sAtom[ADIM];
  for (int d=e; d<ADIM; d+=128) sAtom[d] = atom_table[a*ADIM+d];
  __syncthreads();
  float acc = comp_b[e] + pdd_b[e];
  #pragma unroll 4
  for (int d=0; d<ADIM; d++) acc = fmaf(sAtom[d], comp_W[d*EE+e], acc);
  atom_emb[a*EE+e] = acc;
}

// =================== embed + layer-0 LN (64 tokens/block) ===================
// x = atom_emb[idx] + str[1:]@pdd_W ; xn = LN(x, g0, b0)
__global__ __launch_bounds__(256) void embed_ln_k(
    const float* __restrict__ str_fea, const int* __restrict__ comp_fea,
    const float* __restrict__ atom_emb, const float* __restrict__ pdd_W,
    const float* __restrict__ g, const float* __restrict__ bta,
    float* __restrict__ x, float* __restrict__ x_init, float* __restrict__ w,
    u16* __restrict__ xn)
{
  const int t0 = blockIdx.x*64;
  const int tid = threadIdx.x;
  const int wv = tid>>6, lane = tid&63;
  __shared__ float sPdd[100*EE];       // 51.2 KB
  __shared__ float sStrW[4][104];
  for (int k2=tid; k2<100*EE; k2+=256) sPdd[k2] = pdd_W[k2];
  __syncthreads();
  const float2 gg = ((const float2*)g)[lane];
  const float2 bb = ((const float2*)bta)[lane];
  const int e0 = lane*2;
  #pragma unroll 1
  for (int it=0; it<16; ++it){
    const int t = t0 + wv*16 + it;
    const float* sr0 = str_fea + (size_t)t*KF;
    sStrW[wv][lane] = sr0[lane];
    if (lane+64 < KF) sStrW[wv][lane+64] = sr0[lane+64];
    const float* sr = sStrW[wv];
    const int idx = comp_fea[t];
    const float2 ae = ((const float2*)(atom_emb + (size_t)idx*EE))[lane];
    float a0=ae.x, a1=0.f, a2=0.f, a3=0.f;
    float c0=ae.y, c1=0.f, c2=0.f, c3=0.f;
    #pragma unroll
    for (int j=0; j<100; j+=4){
      a0 = fmaf(sr[1+j], sPdd[(j  )*EE+e0],   a0);
      a1 = fmaf(sr[2+j], sPdd[(j+1)*EE+e0],   a1);
      a2 = fmaf(sr[3+j], sPdd[(j+2)*EE+e0],   a2);
      a3 = fmaf(sr[4+j], sPdd[(j+3)*EE+e0],   a3);
      c0 = fmaf(sr[1+j], sPdd[(j  )*EE+e0+1], c0);
      c1 = fmaf(sr[2+j], sPdd[(j+1)*EE+e0+1], c1);
      c2 = fmaf(sr[3+j], sPdd[(j+2)*EE+e0+1], c2);
      c3 = fmaf(sr[4+j], sPdd[(j+3)*EE+e0+1], c3);
    }
    const float vx = (a0+a1)+(a2+a3);
    const float vy = (c0+c1)+(c2+c3);
    ((float2*)(x      + (size_t)t*EE))[lane] = make_float2(vx, vy);
    ((float2*)(x_init + (size_t)t*EE))[lane] = make_float2(vx, vy);
    if (lane==0) w[t] = sr[0];
    // LN (identical order to old ln_k)
    float s = vx + vy;
    #pragma unroll
    for (int off=32; off; off>>=1) s += __shfl_xor(s, off);
    const float mean = s*(1.0f/128.0f);
    const float d0 = vx-mean, d1 = vy-mean;
    float q = d0*d0 + d1*d1;
    #pragma unroll
    for (int off=32; off; off>>=1) q += __shfl_xor(q, off);
    const float rstd = rsqrtf(q*(1.0f/128.0f) + 1e-5f);
    u16* o = xn + (size_t)t*EE + e0;
    o[0] = f2bf(d0*rstd*gg.x + bb.x);
    o[1] = f2bf(d1*rstd*gg.y + bb.y);
  }
}

// =================== merged weight prep ===================
DI void trans32(const float* __restrict__ W, u16* __restrict__ WT,
                int Nn, int Kk, int srcCol0, int n0, int k0, int tid,
                u16 (&tile)[32][33])
{
  const int lr = tid>>5, lc = tid&31;
  #pragma unroll
  for (int i=0;i<4;i++)
    tile[lr+i*8][lc] = f2bf(W[(size_t)(k0+lr+i*8)*Nn + srcCol0 + lc]);
  __syncthreads();
  #pragma unroll
  for (int i=0;i<4;i++)
    WT[(size_t)(n0+lr+i*8)*Kk + k0 + lc] = tile[lc][lr+i*8];
}

// roles: [0,1152) qkvT | [1152,1200) ffnT | [1200,1584) outWT |
//        [1584,13872) oW cconv | [13872,13908) qkv bias reorder
__global__ __launch_bounds__(256) void prep_k(
    const float* __restrict__ qkv_W, u16* __restrict__ qkvWT,
    const float* __restrict__ ffn_W, u16* __restrict__ ffnWT,
    const float* __restrict__ out_W, u16* __restrict__ outWT,
    const float* __restrict__ o_W,  u16* __restrict__ oWb,
    const float* __restrict__ qkv_b, float* __restrict__ rqkv_b)
{
  __shared__ u16 tile[32][33];
  int bid = blockIdx.x;
  const int tid = threadIdx.x;
  if (bid < 1152){
    const int xb = bid%96, yb = (bid/96)%4, zb = bid/384;
    const int n0 = xb*32, k0 = yb*32;
    int c0;
    if (n0 < 2048) c0 = (n0>>8)*384 + (n0&255);
    else { const int m0 = n0-2048; c0 = (m0>>7)*384 + 256 + (m0&127); }
    trans32(qkv_W + (size_t)zb*EE*3*EHH, qkvWT + (size_t)zb*3*EHH*EE,
            3*EHH, EE, c0, n0, k0, tid, tile);
    return;
  }
  bid -= 1152;
  if (bid < 48){
    const int xb = bid%4, yb = (bid/4)%4, zb = bid/16;
    trans32(ffn_W + (size_t)zb*EE*EE, ffnWT + (size_t)zb*EE*EE,
            EE, EE, xb*32, xb*32, yb*32, tid, tile);
    return;
  }
  bid -= 48;
  if (bid < 384){
    const int xb = bid%4, yb = (bid/4)%32, zb = bid/128;
    trans32(out_W + (size_t)zb*EHH*EE, outWT + (size_t)zb*EE*EHH,
            EE, EHH, xb*32, xb*32, yb*32, tid, tile);
    return;
  }
  bid -= 384;
  if (bid < 12288){
    const int i = bid*256 + tid;
    oWb[i] = f2bf(o_W[i]);
    return;
  }
  bid -= 12288;
  {
    const int l = bid/12;
    const int n = (bid%12)*256 + tid;
    int c;
    if (n < 2048) c = (n>>8)*384 + (n&255);
    else { const int m = n-2048; c = (m>>7)*384 + 256 + (m&127); }
    rqkv_b[(size_t)l*3*EHH + n] = qkv_b[(size_t)l*3*EHH + c];
  }
}

// =================== fb = o_b@out_W + out_b (parallel, layer per block) ===================
__global__ __launch_bounds__(512) void fuse_b_k(
    const float* __restrict__ ob, const float* __restrict__ outW,
    const float* __restrict__ outb, float* __restrict__ fb)
{
  const int ly = blockIdx.x;
  ob   += (size_t)ly*EHH;
  outW += (size_t)ly*EHH*EE;
  const int tid = threadIdx.x;
  const int n = tid & 127, seg = tid >> 7;      // seg 0..3
  float acc = 0.f;
  const int kb = seg*256;
  #pragma unroll 4
  for (int k2=kb; k2<kb+256; ++k2) acc = fmaf(ob[k2], outW[(size_t)k2*EE+n], acc);
  __shared__ float red[512];
  red[tid] = acc;
  __syncthreads();
  if (seg==0)
    fb[(size_t)ly*EE + n] = outb[(size_t)ly*EE + n]
        + ((red[n]+red[128+n]) + (red[256+n]+red[384+n]));
}

// =================== MFMA bf16 GEMM (layer-batched via z strides) ===================
// A: M x Kk bf16 row-major. BT: Nn x Kk bf16 (pre-transposed B).
// EPI 0: store bf16; 4: bf16 transposed store (no bias);
// EPI 7 (QKV router): col<2048 -> ((u16*)C)[row*2048+col];
//                     col>=2048 -> ((u16*)C2)[(col-2048)*Mdim+row] (V^T).
template<int EPI, int BM, int BN, int BK>
__global__ __launch_bounds__(256) void mgemm_k(
    const u16* __restrict__ A, const u16* __restrict__ BT,
    const float* __restrict__ bias, void* __restrict__ Cv,
    int Nn, int Kk, int Mdim, void* __restrict__ C2,
    size_t sA, size_t sBT, size_t sCb)
{
  const int lz = blockIdx.z;
  A  += (size_t)lz*sA;
  BT += (size_t)lz*sBT;
  void* C = (void*)((char*)Cv + (size_t)lz*sCb);

  constexpr int LDK = BK + 8;
  __shared__ u16 As[BM*LDK];
  __shared__ u16 Bs[BN*LDK];
  const int tid = threadIdx.x;
  const int m0 = blockIdx.y*BM, n0 = blockIdx.x*BN;
  constexpr int WMN = (BM>=128)?2:1;
  constexpr int WNN = 4/WMN;
  constexpr int WM = BM/WMN;
  constexpr int WN = BN/WNN;
  constexpr int FM = WM/16, FN = WN/16;
  const int wv = tid>>6, lane = tid&63;
  const int wm = (wv/WNN)*WM;
  const int wn = (wv%WNN)*WN;
  const int lm = lane&15, lq = lane>>4;

  f32x4 acc[FM][FN];
  #pragma unroll
  for (int i=0;i<FM;i++)
    #pragma unroll
    for (int j=0;j<FN;j++) acc[i][j] = (f32x4){0.f,0.f,0.f,0.f};

  constexpr int ACH = BM*BK/8;
  constexpr int BCH = BN*BK/8;

  for (int k0=0; k0<Kk; k0+=BK){
    #pragma unroll
    for (int c = tid; c < ACH; c += 256){
      const int r = c/(BK/8), kg = c - r*(BK/8);
      const float4 v = *(const float4*)(A + (size_t)(m0+r)*Kk + k0 + kg*8);
      *(float4*)&As[r*LDK + kg*8] = v;
    }
    #pragma unroll
    for (int c = tid; c < BCH; c += 256){
      const int r = c/(BK/8), kg = c - r*(BK/8);
      const float4 v = *(const float4*)(BT + (size_t)(n0+r)*Kk + k0 + kg*8);
      *(float4*)&Bs[r*LDK + kg*8] = v;
    }
    __syncthreads();
    #pragma unroll
    for (int kk=0; kk<BK/32; kk++){
      bf16x8 af[FM], bfr[FN];
      #pragma unroll
      for (int i=0;i<FM;i++)
        af[i] = *(const bf16x8*)&As[(wm + i*16 + lm)*LDK + kk*32 + lq*8];
      #pragma unroll
      for (int j=0;j<FN;j++)
        bfr[j] = *(const bf16x8*)&Bs[(wn + j*16 + lm)*LDK + kk*32 + lq*8];
      #pragma unroll
      for (int i=0;i<FM;i++)
        #pragma unroll
        for (int j=0;j<FN;j++)
          acc[i][j] = __builtin_amdgcn_mfma_f32_16x16x32_bf16(af[i], bfr[j], acc[i][j], 0, 0, 0);
    }
    __syncthreads();
  }
  #pragma unroll
  for (int i=0;i<FM;i++){
    #pragma unroll
    for (int j=0;j<FN;j++){
      const int col = n0 + wn + j*16 + lm;
      const float bv = (EPI==4) ? 0.f : bias[col];
      #pragma unroll
      for (int r=0;r<4;r++){
        const int row = m0 + wm + i*16 + lq*4 + r;
        float v = acc[i][j][r] + bv;
        if constexpr (EPI==7){
          if (col < 2048) ((u16*)C)[(size_t)row*2048 + col] = f2bf(v);
          else            ((u16*)C2)[(size_t)(col-2048)*Mdim + row] = f2bf(v);
        } else if constexpr (EPI==4){
          ((u16*)C)[(size_t)col*Mdim + row] = f2bf(v);
        } else {
          ((u16*)C)[(size_t)row*Nn + col] = f2bf(v);
        }
      }
    }
  }
}

// =================== fused proj+LN + ffn+mish + dual-LN ===================
// Phase A: out1 = vals@fwT + fb + x  (K=1024, BK=128, rows m0..m0+31; kept in regs)
//          xn2 = rowLN(out1, g1,b1) -> bf16 in LDS
// Phase B: f = xn2 @ ffnWT + fnb (K=128 from LDS)
// Phase C: t = out1 + mish(f); x = rowLN(t, g1,b1) -> x_io (f32)
//          xn = rowLN(x, g2,b2) -> xn_io (bf16)
__global__ __launch_bounds__(256) void projffn_k(
    const u16* __restrict__ vals, const u16* __restrict__ fwT,
    const float* __restrict__ fb, const u16* __restrict__ ffnWT,
    const float* __restrict__ fnb,
    const float* __restrict__ g1, const float* __restrict__ b1,
    const float* __restrict__ g2, const float* __restrict__ b2,
    float* __restrict__ x_io, u16* __restrict__ xn_io)
{
  constexpr int BM = 32, BK = 128, LDK = BK + 8;
  __shared__ u16 As[BM*LDK];        // proj A tiles; then xn2 (bf16)
  __shared__ u16 Bs[EE*LDK];        // fwT tiles; then ffnWT
  __shared__ float sred[BM*8];
  const int tid = threadIdx.x;
  const int wv = tid>>6, lane = tid&63;
  const int lm = lane&15, lq = lane>>4;
  const int m0 = blockIdx.x*BM;
  const int wn = wv*32;             // 4 waves x 32 cols

  f32x4 acc[2][2];
  #pragma unroll
  for (int i=0;i<2;i++)
    #pragma unroll
    for (int j=0;j<2;j++) acc[i][j] = (f32x4){0.f,0.f,0.f,0.f};

  // ---- phase A: proj GEMM, K=1024 ----
  for (int k0=0; k0<EHH; k0+=BK){
    #pragma unroll
    for (int c = tid; c < BM*BK/8; c += 256){
      const int r = c>>4, kg = c&15;
      *(float4*)&As[r*LDK + kg*8] = *(const float4*)(vals + (size_t)(m0+r)*EHH + k0 + kg*8);
    }
    #pragma unroll
    for (int c = tid; c < EE*BK/8; c += 256){
      const int r = c>>4, kg = c&15;
      *(float4*)&Bs[r*LDK + kg*8] = *(const float4*)(fwT + (size_t)r*EHH + k0 + kg*8);
    }
    __syncthreads();
    #pragma unroll
    for (int kk=0; kk<BK/32; kk++){
      bf16x8 af[2], bfr[2];
      #pragma unroll
      for (int i=0;i<2;i++)
        af[i] = *(const bf16x8*)&As[(i*16 + lm)*LDK + kk*32 + lq*8];
      #pragma unroll
      for (int j=0;j<2;j++)
        bfr[j] = *(const bf16x8*)&Bs[(wn + j*16 + lm)*LDK + kk*32 + lq*8];
      #pragma unroll
      for (int i=0;i<2;i++)
        #pragma unroll
        for (int j=0;j<2;j++)
          acc[i][j] = __builtin_amdgcn_mfma_f32_16x16x32_bf16(af[i], bfr[j], acc[i][j], 0, 0, 0);
    }
    __syncthreads();
  }

  // ---- phase A epilogue: vout = acc + fb + x ; LN stats ----
  float vout[2][2][4];
  float ps[2][4], qs[2][4];
  #pragma unroll
  for (int i=0;i<2;i++)
    #pragma unroll
    for (int r=0;r<4;r++){ ps[i][r]=0.f; qs[i][r]=0.f; }
  #pragma unroll
  for (int i=0;i<2;i++){
    #pragma unroll
    for (int j=0;j<2;j++){
      const int col = wn + j*16 + lm;
      const float bv = fb[col];
      #pragma unroll
      for (int r=0;r<4;r++){
        const int row = m0 + i*16 + lq*4 + r;
        const float v = acc[i][j][r] + bv + x_io[(size_t)row*EE + col];
        vout[i][j][r] = v;
        ps[i][r] += v; qs[i][r] += v*v;
      }
    }
  }
  #pragma unroll
  for (int i=0;i<2;i++)
    #pragma unroll
    for (int r=0;r<4;r++){
      float s = ps[i][r], q = qs[i][r];
      s += __shfl_xor(s,1); s += __shfl_xor(s,2); s += __shfl_xor(s,4); s += __shfl_xor(s,8);
      q += __shfl_xor(q,1); q += __shfl_xor(q,2); q += __shfl_xor(q,4); q += __shfl_xor(q,8);
      if (lm==0){
        const int row = i*16 + lq*4 + r;
        sred[row*4 + wv] = s;
        sred[BM*4 + row*4 + wv] = q;
      }
    }
  __syncthreads();
  // xn2 -> As (bf16), and stage ffnWT -> Bs
  #pragma unroll
  for (int i=0;i<2;i++)
    #pragma unroll
    for (int r=0;r<4;r++){
      const int row = i*16 + lq*4 + r;
      const float s = sred[row*4+0]+sred[row*4+1]+sred[row*4+2]+sred[row*4+3];
      const float q = sred[BM*4+row*4+0]+sred[BM*4+row*4+1]+sred[BM*4+row*4+2]+sred[BM*4+row*4+3];
      const float mean = s*(1.0f/128.0f);
      const float var  = q*(1.0f/128.0f) - mean*mean;
      const float rstd = rsqrtf(var + 1e-5f);
      #pragma unroll
      for (int j=0;j<2;j++){
        const int col = wn + j*16 + lm;
        const float xnv = (vout[i][j][r]-mean)*rstd*g1[col] + b1[col];
        As[row*LDK + col] = f2bf(xnv);
      }
    }
  #pragma unroll
  for (int c = tid; c < EE*EE/8; c += 256){
    const int r = c>>4, kg = c&15;
    *(float4*)&Bs[r*LDK + kg*8] = *(const float4*)(ffnWT + (size_t)r*EE + kg*8);
  }
  __syncthreads();

  // ---- phase B: ffn GEMM, K=128 from LDS ----
  f32x4 fa[2][2];
  #pragma unroll
  for (int i=0;i<2;i++)
    #pragma unroll
    for (int j=0;j<2;j++) fa[i][j] = (f32x4){0.f,0.f,0.f,0.f};
  #pragma unroll
  for (int kk=0; kk<4; kk++){
    bf16x8 af[2], bfr[2];
    #pragma unroll
    for (int i=0;i<2;i++)
      af[i] = *(const bf16x8*)&As[(i*16 + lm)*LDK + kk*32 + lq*8];
    #pragma unroll
    for (int j=0;j<2;j++)
      bfr[j] = *(const bf16x8*)&Bs[(wn + j*16 + lm)*LDK + kk*32 + lq*8];
    #pragma unroll
    for (int i=0;i<2;i++)
      #pragma unroll
      for (int j=0;j<2;j++)
        fa[i][j] = __builtin_amdgcn_mfma_f32_16x16x32_bf16(af[i], bfr[j], fa[i][j], 0, 0, 0);
  }

  // ---- phase C: t = vout + mish(fa + fnb); dual row-LN ----
  float tv[2][2][4];
  #pragma unroll
  for (int i=0;i<2;i++)
    #pragma unroll
    for (int r=0;r<4;r++){ ps[i][r]=0.f; qs[i][r]=0.f; }
  #pragma unroll
  for (int i=0;i<2;i++){
    #pragma unroll
    for (int j=0;j<2;j++){
      const int col = wn + j*16 + lm;
      const float bv = fnb[col];
      #pragma unroll
      for (int r=0;r<4;r++){
        const float v = fa[i][j][r] + bv;
        const float E = __expf(v);
        const float uu = E*E + 2.f*E;
        const float mi = (v > 20.f) ? v : v*(uu/(uu+2.f));
        const float t = vout[i][j][r] + mi;
        tv[i][j][r] = t;
        ps[i][r] += t; qs[i][r] += t*t;
      }
    }
  }
  #pragma unroll
  for (int i=0;i<2;i++)
    #pragma unroll
    for (int r=0;r<4;r++){
      float s = ps[i][r], q = qs[i][r];
      s += __shfl_xor(s,1); s += __shfl_xor(s,2); s += __shfl_xor(s,4); s += __shfl_xor(s,8);
      q += __shfl_xor(q,1); q += __shfl_xor(q,2); q += __shfl_xor(q,4); q += __shfl_xor(q,8);
      if (lm==0){
        const int row = i*16 + lq*4 + r;
        sred[row*4 + wv] = s;
        sred[BM*4 + row*4 + wv] = q;
      }
    }
  __syncthreads();
  float xv[2][2][4];
  float ps2[2][4], qs2[2][4];
  #pragma unroll
  for (int i=0;i<2;i++)
    #pragma unroll
    for (int r=0;r<4;r++){
      const int row = i*16 + lq*4 + r;
      const float s = sred[row*4+0]+sred[row*4+1]+sred[row*4+2]+sred[row*4+3];
      const float q = sred[BM*4+row*4+0]+sred[BM*4+row*4+1]+sred[BM*4+row*4+2]+sred[BM*4+row*4+3];
      const float mean = s*(1.0f/128.0f);
      const float var  = q*(1.0f/128.0f) - mean*mean;
      const float rstd = rsqrtf(var + 1e-5f);
      float s2 = 0.f, q2 = 0.f;
      #pragma unroll
      for (int j=0;j<2;j++){
        const int col = wn + j*16 + lm;
        const float xnv = (tv[i][j][r]-mean)*rstd*g1[col] + b1[col];
        x_io[(size_t)(m0+row)*EE + col] = xnv;
        xv[i][j][r] = xnv;
        s2 += xnv; q2 += xnv*xnv;
      }
      ps2[i][r] = s2; qs2[i][r] = q2;
    }
  __syncthreads();
  #pragma unroll
  for (int i=0;i<2;i++)
    #pragma unroll
    for (int r=0;r<4;r++){
      float s = ps2[i][r], q = qs2[i][r];
      s += __shfl_xor(s,1); s += __shfl_xor(s,2); s += __shfl_xor(s,4); s += __shfl_xor(s,8);
      q += __shfl_xor(q,1); q += __shfl_xor(q,2); q += __shfl_xor(q,4); q += __shfl_xor(q,8);
      if (lm==0){
        const int row = i*16 + lq*4 + r;
        sred[row*4 + wv] = s;
        sred[BM*4 + row*4 + wv] = q;
      }
    }
  __syncthreads();
  #pragma unroll
  for (int i=0;i<2;i++)
    #pragma unroll
    for (int r=0;r<4;r++){
      const int row = i*16 + lq*4 + r;
      const float s = sred[row*4+0]+sred[row*4+1]+sred[row*4+2]+sred[row*4+3];
      const float q = sred[BM*4+row*4+0]+sred[BM*4+row*4+1]+sred[BM*4+row*4+2]+sred[BM*4+row*4+3];
      const float mean = s*(1.0f/128.0f);
      const float var  = q*(1.0f/128.0f) - mean*mean;
      const float rstd = rsqrtf(var + 1e-5f);
      #pragma unroll
      for (int j=0;j<2;j++){
        const int col = wn + j*16 + lm;
        const float xnv = (xv[i][j][r]-mean)*rstd*g2[col] + b2[col];
        xn_io[(size_t)(m0+row)*EE + col] = f2bf(xnv);
      }
    }
}

// =================== MFMA flash attention (XCD-local grid: bl,h,qt) ===================
// qkc: [tok][h*256 + (q:0..127 | k:128..255)] bf16, tok chunk-local.
// vTc: [h*128+d][tok] bf16 (pre-transposed V), tok chunk-local.
__global__ __launch_bounds__(256) void attn_mf_k(
    const u16* __restrict__ qkc, const u16* __restrict__ vTc,
    const float* __restrict__ w, u16* __restrict__ vals_c, int b0)
{
  const int bl = blockIdx.x;   // id%8 = bl -> one XCD per batch
  const int h  = blockIdx.y;
  const int qt = blockIdx.z;
  const int tid = threadIdx.x;
  const int wv = tid>>6, lane = tid&63;
  const int lm = lane&15, lq = lane>>4;

  __shared__ u16 Qs[64][136];
  __shared__ u16 Ks[64][136];
  __shared__ u16 Vts[128][72];
  __shared__ u16 Ps[64][72];
  __shared__ float wt[64], qwt[64];

  const size_t rs = 2048;
  const u16* qk = qkc + (size_t)bl*SEQ*rs + (size_t)h*256;
  const u16* vb = vTc + (size_t)h*128*CTOK + (size_t)bl*SEQ;
  const int q0 = qt*64;

  #pragma unroll
  for (int it=0; it<4; it++){
    const int fi = it*256 + tid;
    const int r = fi >> 4, g = fi & 15;
    *(float4*)&Qs[r][g*8] = *(const float4*)(qk + (size_t)(q0+r)*rs + g*8);
  }
  if (tid < 64) qwt[tid] = w[(b0+bl)*SEQ + q0 + tid];
  __syncthreads();

  float kq[4];
  #pragma unroll
  for (int r=0;r<4;r++) kq[r] = qwt[wv*16 + lq*4 + r];

  f32x4 oacc[8];
  #pragma unroll
  for (int j=0;j<8;j++) oacc[j] = (f32x4){0.f,0.f,0.f,0.f};
  float mrow[4], lrow[4];
  #pragma unroll
  for (int r=0;r<4;r++){ mrow[r]=-INFINITY; lrow[r]=0.f; }
  const float scale = 0.08838834764831845f;  // 1/sqrt(128)

  for (int kt=0; kt<8; kt++){
    __syncthreads();
    #pragma unroll
    for (int it=0; it<4; it++){
      const int fi = it*256 + tid;
      const int r = fi >> 4, g = fi & 15;
      *(float4*)&Ks[r][g*8] = *(const float4*)(qk + (size_t)(kt*64+r)*rs + 128 + g*8);
    }
    #pragma unroll
    for (int it=0; it<4; it++){
      const int fi = it*256 + tid;
      const int d = fi >> 3, g = fi & 7;
      *(float4*)&Vts[d][g*8] = *(const float4*)(vb + (size_t)d*CTOK + kt*64 + g*8);
    }
    if (tid < 64) wt[tid] = w[(b0+bl)*SEQ + kt*64 + tid];
    __syncthreads();

    f32x4 sacc[4];
    #pragma unroll
    for (int j=0;j<4;j++) sacc[j] = (f32x4){0.f,0.f,0.f,0.f};
    #pragma unroll
    for (int kk=0; kk<4; kk++){
      const bf16x8 af = *(const bf16x8*)&Qs[wv*16+lm][kk*32+lq*8];
      #pragma unroll
      for (int j=0;j<4;j++){
        const bf16x8 bf = *(const bf16x8*)&Ks[j*16+lm][kk*32+lq*8];
        sacc[j] = __builtin_amdgcn_mfma_f32_16x16x32_bf16(af, bf, sacc[j], 0, 0, 0);
      }
    }
    float wkj[4], s[4][4];
    #pragma unroll
    for (int j=0;j<4;j++) wkj[j] = wt[j*16+lm];
    #pragma unroll
    for (int j=0;j<4;j++)
      #pragma unroll
      for (int r=0;r<4;r++){
        const bool keep = (kq[r] > 0.f) && (wkj[j] > 0.f);
        s[j][r] = keep ? sacc[j][r]*scale : -9.0e15f;
      }
    float alpha[4];
    #pragma unroll
    for (int r=0;r<4;r++){
      float rm = fmaxf(fmaxf(s[0][r], s[1][r]), fmaxf(s[2][r], s[3][r]));
      rm = fmaxf(rm, __shfl_xor(rm, 1));
      rm = fmaxf(rm, __shfl_xor(rm, 2));
      rm = fmaxf(rm, __shfl_xor(rm, 4));
      rm = fmaxf(rm, __shfl_xor(rm, 8));
      const float newm = fmaxf(mrow[r], rm);
      alpha[r] = __expf(mrow[r] - newm);
      float ls = 0.f;
      #pragma unroll
      for (int j=0;j<4;j++){
        const float pv = wkj[j]*__expf(s[j][r]-newm);
        s[j][r] = pv; ls += pv;
      }
      ls += __shfl_xor(ls, 1);
      ls += __shfl_xor(ls, 2);
      ls += __shfl_xor(ls, 4);
      ls += __shfl_xor(ls, 8);
      lrow[r] = lrow[r]*alpha[r] + ls;
      mrow[r] = newm;
    }
    #pragma unroll
    for (int j=0;j<4;j++)
      #pragma unroll
      for (int r=0;r<4;r++)
        Ps[wv*16 + lq*4 + r][j*16+lm] = f2bf(s[j][r]);
    #pragma unroll
    for (int j=0;j<8;j++)
      #pragma unroll
      for (int r=0;r<4;r++) oacc[j][r] *= alpha[r];
    __syncthreads();

    #pragma unroll
    for (int kk=0; kk<2; kk++){
      const bf16x8 pf = *(const bf16x8*)&Ps[wv*16+lm][kk*32+lq*8];
      #pragma unroll
      for (int j=0;j<8;j++){
        const bf16x8 vf = *(const bf16x8*)&Vts[j*16+lm][kk*32+lq*8];
        oacc[j] = __builtin_amdgcn_mfma_f32_16x16x32_bf16(pf, vf, oacc[j], 0, 0, 0);
      }
    }
  }
  #pragma unroll
  for (int r=0;r<4;r++){
    const float inv = 1.0f / lrow[r];
    u16* orow = vals_c + ((size_t)(bl*SEQ + q0 + wv*16 + lq*4 + r))*EHH + h*EE;
    #pragma unroll
    for (int j=0;j<8;j++) orow[j*16+lm] = f2bf(oacc[j][r]*inv);
  }
}

// =================== fused pool: weighted sum + LN + head ===================
__global__ __launch_bounds__(128) void pool_k(
    const float* __restrict__ x, const float* __restrict__ x_init,
    const float* __restrict__ w, const float* __restrict__ g2,
    const float* __restrict__ b2, const float* __restrict__ head_W,
    const float* __restrict__ head_b, float* __restrict__ out)
{
  const int b = blockIdx.x;
  const int e = threadIdx.x;
  float acc = 0.f;
  #pragma unroll 4
  for (int n=0;n<SEQ;n++){
    const int tok = b*SEQ + n;
    const size_t idx = (size_t)tok*EE + e;
    acc = fmaf(w[tok], x[idx]+x_init[idx], acc);
  }
  __shared__ float red[128];
  red[e]=acc; __syncthreads();
  for (int s=64;s>0;s>>=1){ if(e<s) red[e]+=red[e+s]; __syncthreads(); }
  const float mean = red[0]*(1.0f/128.0f);
  __syncthreads();
  const float d = acc-mean;
  red[e]=d*d; __syncthreads();
  for (int s=64;s>0;s>>=1){ if(e<s) red[e]+=red[e+s]; __syncthreads(); }
  const float var = red[0]*(1.0f/128.0f);
  const float p = d*rsqrtf(var+1e-5f)*g2[e]+b2[e];
  __syncthreads();
  red[e] = p*head_W[e]; __syncthreads();
  for (int s=64;s>0;s>>=1){ if(e<s) red[e]+=red[e+s]; __syncthreads(); }
  if (e==0) out[b] = red[0] + head_b[0];
}

// =================== launch ===================
extern "C" void kernel_launch(void* const* d_in, const int* in_sizes, int n_in,
                              void* d_out, int out_size, void* d_ws, size_t ws_size,
                              hipStream_t stream)
{
  const float* str_fea   = (const float*)d_in[0];
  const int*   comp_fea  = (const int*)  d_in[1];
  // d_in[2] cell_fea unused by reference
  const float* atom_table= (const float*)d_in[3];
  const float* comp_W    = (const float*)d_in[4];
  const float* comp_b    = (const float*)d_in[5];
  const float* pdd_W     = (const float*)d_in[6];
  const float* pdd_b     = (const float*)d_in[7];
  const float* enc_ln_g  = (const float*)d_in[8];
  const float* enc_ln_b  = (const float*)d_in[9];
  const float* qkv_W     = (const float*)d_in[10];
  const float* qkv_b     = (const float*)d_in[11];
  const float* o_W       = (const float*)d_in[12];
  const float* o_b       = (const float*)d_in[13];
  const float* out_W     = (const float*)d_in[14];
  const float* out_b     = (const float*)d_in[15];
  const float* ffn_W     = (const float*)d_in[16];
  const float* ffn_b     = (const float*)d_in[17];
  const float* ln2_g     = (const float*)d_in[18];
  const float* ln2_b     = (const float*)d_in[19];
  const float* head_W    = (const float*)d_in[20];
  const float* head_b    = (const float*)d_in[21];
  float* out = (float*)d_out;

  // ---- diagnostic 1: input layout model ----
  bool sizes_ok = (n_in >= 22);
  if (sizes_ok){
    sizes_ok = in_sizes[0]==BB*SEQ*KF && in_sizes[1]==NTOK &&
               in_sizes[3]==NATOM*ADIM && in_sizes[4]==ADIM*EE &&
               in_sizes[10]==LL*EE*3*EHH && in_sizes[12]==LL*EHH*EHH &&
               in_sizes[14]==LL*EHH*EE   && in_sizes[16]==LL*EE*EE &&
               in_sizes[20]==EE;
  }
  if (!sizes_ok){
    sentinel_k<<<(out_size+63)/64,64,0,stream>>>(out, 99999.0f, out_size);
    return;
  }

  // ---- workspace layout (~90 MB; <= 109.7 MB proven) ----
  char* p = (char*)d_ws;
  size_t off = 0;
  auto alloc = [&](size_t bytes)->void*{
    off = (off + 255) & ~(size_t)255;
    void* r = p + off; off += bytes; return r;
  };
  float* w        = (float*)alloc((size_t)NTOK*4);
  float* x        = (float*)alloc((size_t)NTOK*EE*4);
  float* x_init   = (float*)alloc((size_t)NTOK*EE*4);
  u16*   xn_bf    = (u16*)  alloc((size_t)NTOK*EE*2);
  u16*   qkc      = (u16*)  alloc((size_t)CTOK*2048*2);   // 16.8 MB chunk (Q|K)
  u16*   vTc      = (u16*)  alloc((size_t)EHH*CTOK*2);    // 8.4 MB chunk (V^T)
  u16*   vals_bf  = (u16*)  alloc((size_t)NTOK*EHH*2);    // 33.6 MB
  u16*   qkvWT_a  = (u16*)  alloc((size_t)LL*3*EHH*EE*2); // 2.36 MB (reordered)
  float* rqkv_b   = (float*)alloc((size_t)LL*3*EHH*4);    // reordered bias
  u16*   fwT_a    = (u16*)  alloc((size_t)LL*EE*EHH*2);   // 0.79 MB
  u16*   ffnWT_a  = (u16*)  alloc((size_t)LL*EE*EE*2);
  u16*   oWb_a    = (u16*)  alloc((size_t)LL*EHH*EHH*2);  // 6.29 MB
  u16*   outWT_a  = (u16*)  alloc((size_t)LL*EE*EHH*2);
  float* fb_a     = (float*)alloc((size_t)LL*EE*4);
  float* atom_emb = (float*)alloc((size_t)NATOM*EE*4);

  // ---- diagnostic 2: workspace size ----
  if (off > ws_size){
    sentinel_k<<<(out_size+63)/64,64,0,stream>>>(out, 12345.0f, out_size);
    return;
  }

  // ---- hoisted weight prep (merged) ----
  prep_k<<<13908,256,0,stream>>>(qkv_W, qkvWT_a, ffn_W, ffnWT_a,
                                 out_W, outWT_a, o_W, oWb_a, qkv_b, rqkv_b);
  fuse_b_k<<<LL,512,0,stream>>>(o_b, out_W, out_b, fb_a);
  // fwT = (o_W @ out_W)^T per layer (EPI4 transposed store), grid.z = layers
  mgemm_k<4,32,128,128><<<dim3(1, EHH/32, LL),256,0,stream>>>(
      oWb_a, outWT_a, nullptr, fwT_a, EE, EHH, EHH, nullptr,
      (size_t)EHH*EHH, (size_t)EE*EHH, (size_t)EE*EHH*2);

  atomemb_k<<<NATOM,128,0,stream>>>(atom_table, comp_W, comp_b, pdd_b, atom_emb);
  embed_ln_k<<<NTOK/64,256,0,stream>>>(str_fea, comp_fea, atom_emb, pdd_W,
                                       enc_ln_g, enc_ln_b, x, x_init, w, xn_bf);

  for (int i=0;i<LL;i++){
    const float* gi = enc_ln_g + i*EE;
    const float* bi = enc_ln_b + i*EE;
    for (int cb=0; cb<NCHUNK; cb++){
      const int t0 = cb*CTOK;
      const int b0 = cb*CB;
      // QKV with router epilogue: Q|K -> qkc (stride 2048), V -> vTc (transposed)
      mgemm_k<7,128,128,64><<<dim3(3*EHH/128, CTOK/128),256,0,stream>>>(
          xn_bf + (size_t)t0*EE, qkvWT_a + (size_t)i*3*EHH*EE,
          rqkv_b + (size_t)i*3*EHH,
          qkc, 3*EHH, EE, CTOK, vTc, 0, 0, 0);
      attn_mf_k<<<dim3(CB, HH, SEQ/64),256,0,stream>>>(
          qkc, vTc, w, vals_bf + (size_t)t0*EHH, b0);
    }
    // proj + resid + LN + ffn + mish + dual-LN, all in one kernel
    const float* gn = (i<LL-1) ? enc_ln_g + (i+1)*EE : gi;
    const float* bn = (i<LL-1) ? enc_ln_b + (i+1)*EE : bi;
    projffn_k<<<NTOK/32,256,0,stream>>>(
        vals_bf, fwT_a + (size_t)i*EE*EHH, fb_a + (size_t)i*EE,
        ffnWT_a + (size_t)i*EE*EE, ffn_b + (size_t)i*EE,
        gi, bi, gn, bn, x, xn_bf);
  }
  pool_k<<<BB,128,0,stream>>>(x, x_init, w, ln2_g, ln2_b, head_W, head_b, out);
}

// Round 4
// 929.815 us; speedup vs baseline: 1.1521x; 1.0441x over previous
//
#include <hip/hip_runtime.h>
#include <math.h>

#define DI __device__ __forceinline__

// ---- problem constants ----
#define BB 32
#define SEQ 512
#define KF 101
#define EE 128
#define HH 8
#define EHH 1024
#define LL 3
#define ADIM 200
#define NATOM 119
#define NTOK (BB*SEQ)   // 16384
#define CB 8            // batches per chunk
#define NCHUNK (BB/CB)  // 4
#define CTOK (CB*SEQ)   // 4096 tokens per chunk

// R18 = R17 resubmit (infra failure, no counters). R17: latency-bound
// straggler fixes. embed_ln 1024thr/16 waves (was 4 waves 1/CU grinding
// 200 LDS-fed FMAs x16 tokens serially = 43us @ 7% HBM); pool 512thr
// 4-way split; atomemb 256thr 2-way d-split; fwT prep BN=64 (96->192
// blocks); attn: mid-barrier removed (P LDS round-trip is wave-local ->
// in-order DS pipeline suffices), s_setprio around MFMA clusters (T5).

typedef unsigned short u16;
typedef __attribute__((ext_vector_type(8))) short bf16x8;
typedef __attribute__((ext_vector_type(4))) float f32x4;

DI float bf2f(u16 s){ union{unsigned int u; float f;} x; x.u = ((unsigned int)s)<<16; return x.f; }
DI u16 f2bf(float f){
  union{float f; unsigned int u;} x; x.f = f;
  unsigned int u = x.u;
  u += 0x7fffu + ((u>>16)&1u);           // RNE
  return (u16)(u>>16);
}

// =================== sentinel ===================
__global__ void sentinel_k(float* out, float v, int n){
  int i = blockIdx.x*64 + threadIdx.x;
  if (i < n) out[i] = v;
}

// =================== atom embedding precompute (2-way d-split) ===================
__global__ __launch_bounds__(256) void atomemb_k(
    const float* __restrict__ atom_table, const float* __restrict__ comp_W,
    const float* __restrict__ comp_b, const float* __restrict__ pdd_b,
    float* __restrict__ atom_emb)
{
  const int a = blockIdx.x;      // 0..NATOM-1
  const int tid = threadIdx.x;
  const int e = tid & 127, half = tid >> 7;
  __shared__ float sAtom[ADIM];
  __shared__ float red[256];
  for (int d=tid; d<ADIM; d+=256) sAtom[d] = atom_table[a*ADIM+d];
  __syncthreads();
  float acc = half ? 0.f : (comp_b[e] + pdd_b[e]);
  const int d0 = half*100;
  #pragma unroll 4
  for (int d=d0; d<d0+100; d++) acc = fmaf(sAtom[d], comp_W[d*EE+e], acc);
  red[tid] = acc;
  __syncthreads();
  if (half==0) atom_emb[a*EE+e] = red[e] + red[128+e];
}

// =================== embed + layer-0 LN (64 tokens/block, 16 waves) ===================
// x = atom_emb[idx] + str[1:]@pdd_W ; xn = LN(x, g0, b0)
__global__ __launch_bounds__(1024) void embed_ln_k(
    const float* __restrict__ str_fea, const int* __restrict__ comp_fea,
    const float* __restrict__ atom_emb, const float* __restrict__ pdd_W,
    const float* __restrict__ g, const float* __restrict__ bta,
    float* __restrict__ x, float* __restrict__ x_init, float* __restrict__ w,
    u16* __restrict__ xn)
{
  const int t0 = blockIdx.x*64;
  const int tid = threadIdx.x;
  const int wv = tid>>6, lane = tid&63;
  __shared__ float sPdd[100*EE];       // 51.2 KB
  __shared__ float sStrW[16][104];
  for (int k2=tid; k2<100*EE; k2+=1024) sPdd[k2] = pdd_W[k2];
  __syncthreads();
  const float2 gg = ((const float2*)g)[lane];
  const float2 bb = ((const float2*)bta)[lane];
  const int e0 = lane*2;
  #pragma unroll 1
  for (int it=0; it<4; ++it){
    const int t = t0 + wv*4 + it;
    const float* sr0 = str_fea + (size_t)t*KF;
    sStrW[wv][lane] = sr0[lane];
    if (lane+64 < KF) sStrW[wv][lane+64] = sr0[lane+64];
    const float* sr = sStrW[wv];
    const int idx = comp_fea[t];
    const float2 ae = ((const float2*)(atom_emb + (size_t)idx*EE))[lane];
    float a0=ae.x, a1=0.f, a2=0.f, a3=0.f;
    float c0=ae.y, c1=0.f, c2=0.f, c3=0.f;
    #pragma unroll
    for (int j=0; j<100; j+=4){
      a0 = fmaf(sr[1+j], sPdd[(j  )*EE+e0],   a0);
      a1 = fmaf(sr[2+j], sPdd[(j+1)*EE+e0],   a1);
      a2 = fmaf(sr[3+j], sPdd[(j+2)*EE+e0],   a2);
      a3 = fmaf(sr[4+j], sPdd[(j+3)*EE+e0],   a3);
      c0 = fmaf(sr[1+j], sPdd[(j  )*EE+e0+1], c0);
      c1 = fmaf(sr[2+j], sPdd[(j+1)*EE+e0+1], c1);
      c2 = fmaf(sr[3+j], sPdd[(j+2)*EE+e0+1], c2);
      c3 = fmaf(sr[4+j], sPdd[(j+3)*EE+e0+1], c3);
    }
    const float vx = (a0+a1)+(a2+a3);
    const float vy = (c0+c1)+(c2+c3);
    ((float2*)(x      + (size_t)t*EE))[lane] = make_float2(vx, vy);
    ((float2*)(x_init + (size_t)t*EE))[lane] = make_float2(vx, vy);
    if (lane==0) w[t] = sr[0];
    // LN (identical order to old ln_k)
    float s = vx + vy;
    #pragma unroll
    for (int off=32; off; off>>=1) s += __shfl_xor(s, off);
    const float mean = s*(1.0f/128.0f);
    const float d0 = vx-mean, d1 = vy-mean;
    float q = d0*d0 + d1*d1;
    #pragma unroll
    for (int off=32; off; off>>=1) q += __shfl_xor(q, off);
    const float rstd = rsqrtf(q*(1.0f/128.0f) + 1e-5f);
    u16* o = xn + (size_t)t*EE + e0;
    o[0] = f2bf(d0*rstd*gg.x + bb.x);
    o[1] = f2bf(d1*rstd*gg.y + bb.y);
  }
}

// =================== merged weight prep ===================
DI void trans32(const float* __restrict__ W, u16* __restrict__ WT,
                int Nn, int Kk, int srcCol0, int n0, int k0, int tid,
                u16 (&tile)[32][33])
{
  const int lr = tid>>5, lc = tid&31;
  #pragma unroll
  for (int i=0;i<4;i++)
    tile[lr+i*8][lc] = f2bf(W[(size_t)(k0+lr+i*8)*Nn + srcCol0 + lc]);
  __syncthreads();
  #pragma unroll
  for (int i=0;i<4;i++)
    WT[(size_t)(n0+lr+i*8)*Kk + k0 + lc] = tile[lc][lr+i*8];
}

// roles: [0,1152) qkvT | [1152,1200) ffnT | [1200,1584) outWT |
//        [1584,13872) oW cconv | [13872,13908) qkv bias reorder
__global__ __launch_bounds__(256) void prep_k(
    const float* __restrict__ qkv_W, u16* __restrict__ qkvWT,
    const float* __restrict__ ffn_W, u16* __restrict__ ffnWT,
    const float* __restrict__ out_W, u16* __restrict__ outWT,
    const float* __restrict__ o_W,  u16* __restrict__ oWb,
    const float* __restrict__ qkv_b, float* __restrict__ rqkv_b)
{
  __shared__ u16 tile[32][33];
  int bid = blockIdx.x;
  const int tid = threadIdx.x;
  if (bid < 1152){
    const int xb = bid%96, yb = (bid/96)%4, zb = bid/384;
    const int n0 = xb*32, k0 = yb*32;
    int c0;
    if (n0 < 2048) c0 = (n0>>8)*384 + (n0&255);
    else { const int m0 = n0-2048; c0 = (m0>>7)*384 + 256 + (m0&127); }
    trans32(qkv_W + (size_t)zb*EE*3*EHH, qkvWT + (size_t)zb*3*EHH*EE,
            3*EHH, EE, c0, n0, k0, tid, tile);
    return;
  }
  bid -= 1152;
  if (bid < 48){
    const int xb = bid%4, yb = (bid/4)%4, zb = bid/16;
    trans32(ffn_W + (size_t)zb*EE*EE, ffnWT + (size_t)zb*EE*EE,
            EE, EE, xb*32, xb*32, yb*32, tid, tile);
    return;
  }
  bid -= 48;
  if (bid < 384){
    const int xb = bid%4, yb = (bid/4)%32, zb = bid/128;
    trans32(out_W + (size_t)zb*EHH*EE, outWT + (size_t)zb*EE*EHH,
            EE, EHH, xb*32, xb*32, yb*32, tid, tile);
    return;
  }
  bid -= 384;
  if (bid < 12288){
    const int i = bid*256 + tid;
    oWb[i] = f2bf(o_W[i]);
    return;
  }
  bid -= 12288;
  {
    const int l = bid/12;
    const int n = (bid%12)*256 + tid;
    int c;
    if (n < 2048) c = (n>>8)*384 + (n&255);
    else { const int m = n-2048; c = (m>>7)*384 + 256 + (m&127); }
    rqkv_b[(size_t)l*3*EHH + n] = qkv_b[(size_t)l*3*EHH + c];
  }
}

// =================== fb = o_b@out_W + out_b (parallel, layer per block) ===================
__global__ __launch_bounds__(512) void fuse_b_k(
    const float* __restrict__ ob, const float* __restrict__ outW,
    const float* __restrict__ outb, float* __restrict__ fb)
{
  const int ly = blockIdx.x;
  ob   += (size_t)ly*EHH;
  outW += (size_t)ly*EHH*EE;
  const int tid = threadIdx.x;
  const int n = tid & 127, seg = tid >> 7;      // seg 0..3
  float acc = 0.f;
  const int kb = seg*256;
  #pragma unroll 4
  for (int k2=kb; k2<kb+256; ++k2) acc = fmaf(ob[k2], outW[(size_t)k2*EE+n], acc);
  __shared__ float red[512];
  red[tid] = acc;
  __syncthreads();
  if (seg==0)
    fb[(size_t)ly*EE + n] = outb[(size_t)ly*EE + n]
        + ((red[n]+red[128+n]) + (red[256+n]+red[384+n]));
}

// =================== MFMA bf16 GEMM (layer-batched via z strides) ===================
// A: M x Kk bf16 row-major. BT: Nn x Kk bf16 (pre-transposed B).
// EPI 0: store bf16; 4: bf16 transposed store (no bias);
// EPI 7 (QKV router): col<2048 -> ((u16*)C)[row*2048+col];
//                     col>=2048 -> ((u16*)C2)[(col-2048)*Mdim+row] (V^T).
template<int EPI, int BM, int BN, int BK>
__global__ __launch_bounds__(256) void mgemm_k(
    const u16* __restrict__ A, const u16* __restrict__ BT,
    const float* __restrict__ bias, void* __restrict__ Cv,
    int Nn, int Kk, int Mdim, void* __restrict__ C2,
    size_t sA, size_t sBT, size_t sCb)
{
  const int lz = blockIdx.z;
  A  += (size_t)lz*sA;
  BT += (size_t)lz*sBT;
  void* C = (void*)((char*)Cv + (size_t)lz*sCb);

  constexpr int LDK = BK + 8;
  __shared__ u16 As[BM*LDK];
  __shared__ u16 Bs[BN*LDK];
  const int tid = threadIdx.x;
  const int m0 = blockIdx.y*BM, n0 = blockIdx.x*BN;
  constexpr int WMN = (BM>=128)?2:1;
  constexpr int WNN = 4/WMN;
  constexpr int WM = BM/WMN;
  constexpr int WN = BN/WNN;
  constexpr int FM = WM/16, FN = WN/16;
  const int wv = tid>>6, lane = tid&63;
  const int wm = (wv/WNN)*WM;
  const int wn = (wv%WNN)*WN;
  const int lm = lane&15, lq = lane>>4;

  f32x4 acc[FM][FN];
  #pragma unroll
  for (int i=0;i<FM;i++)
    #pragma unroll
    for (int j=0;j<FN;j++) acc[i][j] = (f32x4){0.f,0.f,0.f,0.f};

  constexpr int ACH = BM*BK/8;
  constexpr int BCH = BN*BK/8;

  for (int k0=0; k0<Kk; k0+=BK){
    #pragma unroll
    for (int c = tid; c < ACH; c += 256){
      const int r = c/(BK/8), kg = c - r*(BK/8);
      const float4 v = *(const float4*)(A + (size_t)(m0+r)*Kk + k0 + kg*8);
      *(float4*)&As[r*LDK + kg*8] = v;
    }
    #pragma unroll
    for (int c = tid; c < BCH; c += 256){
      const int r = c/(BK/8), kg = c - r*(BK/8);
      const float4 v = *(const float4*)(BT + (size_t)(n0+r)*Kk + k0 + kg*8);
      *(float4*)&Bs[r*LDK + kg*8] = v;
    }
    __syncthreads();
    #pragma unroll
    for (int kk=0; kk<BK/32; kk++){
      bf16x8 af[FM], bfr[FN];
      #pragma unroll
      for (int i=0;i<FM;i++)
        af[i] = *(const bf16x8*)&As[(wm + i*16 + lm)*LDK + kk*32 + lq*8];
      #pragma unroll
      for (int j=0;j<FN;j++)
        bfr[j] = *(const bf16x8*)&Bs[(wn + j*16 + lm)*LDK + kk*32 + lq*8];
      #pragma unroll
      for (int i=0;i<FM;i++)
        #pragma unroll
        for (int j=0;j<FN;j++)
          acc[i][j] = __builtin_amdgcn_mfma_f32_16x16x32_bf16(af[i], bfr[j], acc[i][j], 0, 0, 0);
    }
    __syncthreads();
  }
  #pragma unroll
  for (int i=0;i<FM;i++){
    #pragma unroll
    for (int j=0;j<FN;j++){
      const int col = n0 + wn + j*16 + lm;
      const float bv = (EPI==4) ? 0.f : bias[col];
      #pragma unroll
      for (int r=0;r<4;r++){
        const int row = m0 + wm + i*16 + lq*4 + r;
        float v = acc[i][j][r] + bv;
        if constexpr (EPI==7){
          if (col < 2048) ((u16*)C)[(size_t)row*2048 + col] = f2bf(v);
          else            ((u16*)C2)[(size_t)(col-2048)*Mdim + row] = f2bf(v);
        } else if constexpr (EPI==4){
          ((u16*)C)[(size_t)col*Mdim + row] = f2bf(v);
        } else {
          ((u16*)C)[(size_t)row*Nn + col] = f2bf(v);
        }
      }
    }
  }
}

// =================== fused proj+LN + ffn+mish + dual-LN ===================
__global__ __launch_bounds__(256) void projffn_k(
    const u16* __restrict__ vals, const u16* __restrict__ fwT,
    const float* __restrict__ fb, const u16* __restrict__ ffnWT,
    const float* __restrict__ fnb,
    const float* __restrict__ g1, const float* __restrict__ b1,
    const float* __restrict__ g2, const float* __restrict__ b2,
    float* __restrict__ x_io, u16* __restrict__ xn_io)
{
  constexpr int BM = 32, BK = 128, LDK = BK + 8;
  __shared__ u16 As[BM*LDK];        // proj A tiles; then xn2 (bf16)
  __shared__ u16 Bs[EE*LDK];        // fwT tiles; then ffnWT
  __shared__ float sred[BM*8];
  const int tid = threadIdx.x;
  const int wv = tid>>6, lane = tid&63;
  const int lm = lane&15, lq = lane>>4;
  const int m0 = blockIdx.x*BM;
  const int wn = wv*32;             // 4 waves x 32 cols

  f32x4 acc[2][2];
  #pragma unroll
  for (int i=0;i<2;i++)
    #pragma unroll
    for (int j=0;j<2;j++) acc[i][j] = (f32x4){0.f,0.f,0.f,0.f};

  // ---- phase A: proj GEMM, K=1024 ----
  for (int k0=0; k0<EHH; k0+=BK){
    #pragma unroll
    for (int c = tid; c < BM*BK/8; c += 256){
      const int r = c>>4, kg = c&15;
      *(float4*)&As[r*LDK + kg*8] = *(const float4*)(vals + (size_t)(m0+r)*EHH + k0 + kg*8);
    }
    #pragma unroll
    for (int c = tid; c < EE*BK/8; c += 256){
      const int r = c>>4, kg = c&15;
      *(float4*)&Bs[r*LDK + kg*8] = *(const float4*)(fwT + (size_t)r*EHH + k0 + kg*8);
    }
    __syncthreads();
    #pragma unroll
    for (int kk=0; kk<BK/32; kk++){
      bf16x8 af[2], bfr[2];
      #pragma unroll
      for (int i=0;i<2;i++)
        af[i] = *(const bf16x8*)&As[(i*16 + lm)*LDK + kk*32 + lq*8];
      #pragma unroll
      for (int j=0;j<2;j++)
        bfr[j] = *(const bf16x8*)&Bs[(wn + j*16 + lm)*LDK + kk*32 + lq*8];
      #pragma unroll
      for (int i=0;i<2;i++)
        #pragma unroll
        for (int j=0;j<2;j++)
          acc[i][j] = __builtin_amdgcn_mfma_f32_16x16x32_bf16(af[i], bfr[j], acc[i][j], 0, 0, 0);
    }
    __syncthreads();
  }

  // ---- phase A epilogue: vout = acc + fb + x ; LN stats ----
  float vout[2][2][4];
  float ps[2][4], qs[2][4];
  #pragma unroll
  for (int i=0;i<2;i++)
    #pragma unroll
    for (int r=0;r<4;r++){ ps[i][r]=0.f; qs[i][r]=0.f; }
  #pragma unroll
  for (int i=0;i<2;i++){
    #pragma unroll
    for (int j=0;j<2;j++){
      const int col = wn + j*16 + lm;
      const float bv = fb[col];
      #pragma unroll
      for (int r=0;r<4;r++){
        const int row = m0 + i*16 + lq*4 + r;
        const float v = acc[i][j][r] + bv + x_io[(size_t)row*EE + col];
        vout[i][j][r] = v;
        ps[i][r] += v; qs[i][r] += v*v;
      }
    }
  }
  #pragma unroll
  for (int i=0;i<2;i++)
    #pragma unroll
    for (int r=0;r<4;r++){
      float s = ps[i][r], q = qs[i][r];
      s += __shfl_xor(s,1); s += __shfl_xor(s,2); s += __shfl_xor(s,4); s += __shfl_xor(s,8);
      q += __shfl_xor(q,1); q += __shfl_xor(q,2); q += __shfl_xor(q,4); q += __shfl_xor(q,8);
      if (lm==0){
        const int row = i*16 + lq*4 + r;
        sred[row*4 + wv] = s;
        sred[BM*4 + row*4 + wv] = q;
      }
    }
  __syncthreads();
  // xn2 -> As (bf16), and stage ffnWT -> Bs
  #pragma unroll
  for (int i=0;i<2;i++)
    #pragma unroll
    for (int r=0;r<4;r++){
      const int row = i*16 + lq*4 + r;
      const float s = sred[row*4+0]+sred[row*4+1]+sred[row*4+2]+sred[row*4+3];
      const float q = sred[BM*4+row*4+0]+sred[BM*4+row*4+1]+sred[BM*4+row*4+2]+sred[BM*4+row*4+3];
      const float mean = s*(1.0f/128.0f);
      const float var  = q*(1.0f/128.0f) - mean*mean;
      const float rstd = rsqrtf(var + 1e-5f);
      #pragma unroll
      for (int j=0;j<2;j++){
        const int col = wn + j*16 + lm;
        const float xnv = (vout[i][j][r]-mean)*rstd*g1[col] + b1[col];
        As[row*LDK + col] = f2bf(xnv);
      }
    }
  #pragma unroll
  for (int c = tid; c < EE*EE/8; c += 256){
    const int r = c>>4, kg = c&15;
    *(float4*)&Bs[r*LDK + kg*8] = *(const float4*)(ffnWT + (size_t)r*EE + kg*8);
  }
  __syncthreads();

  // ---- phase B: ffn GEMM, K=128 from LDS ----
  f32x4 fa[2][2];
  #pragma unroll
  for (int i=0;i<2;i++)
    #pragma unroll
    for (int j=0;j<2;j++) fa[i][j] = (f32x4){0.f,0.f,0.f,0.f};
  #pragma unroll
  for (int kk=0; kk<4; kk++){
    bf16x8 af[2], bfr[2];
    #pragma unroll
    for (int i=0;i<2;i++)
      af[i] = *(const bf16x8*)&As[(i*16 + lm)*LDK + kk*32 + lq*8];
    #pragma unroll
    for (int j=0;j<2;j++)
      bfr[j] = *(const bf16x8*)&Bs[(wn + j*16 + lm)*LDK + kk*32 + lq*8];
    #pragma unroll
    for (int i=0;i<2;i++)
      #pragma unroll
      for (int j=0;j<2;j++)
        fa[i][j] = __builtin_amdgcn_mfma_f32_16x16x32_bf16(af[i], bfr[j], fa[i][j], 0, 0, 0);
  }

  // ---- phase C: t = vout + mish(fa + fnb); dual row-LN ----
  float tv[2][2][4];
  #pragma unroll
  for (int i=0;i<2;i++)
    #pragma unroll
    for (int r=0;r<4;r++){ ps[i][r]=0.f; qs[i][r]=0.f; }
  #pragma unroll
  for (int i=0;i<2;i++){
    #pragma unroll
    for (int j=0;j<2;j++){
      const int col = wn + j*16 + lm;
      const float bv = fnb[col];
      #pragma unroll
      for (int r=0;r<4;r++){
        const float v = fa[i][j][r] + bv;
        const float E = __expf(v);
        const float uu = E*E + 2.f*E;
        const float mi = (v > 20.f) ? v : v*(uu/(uu+2.f));
        const float t = vout[i][j][r] + mi;
        tv[i][j][r] = t;
        ps[i][r] += t; qs[i][r] += t*t;
      }
    }
  }
  #pragma unroll
  for (int i=0;i<2;i++)
    #pragma unroll
    for (int r=0;r<4;r++){
      float s = ps[i][r], q = qs[i][r];
      s += __shfl_xor(s,1); s += __shfl_xor(s,2); s += __shfl_xor(s,4); s += __shfl_xor(s,8);
      q += __shfl_xor(q,1); q += __shfl_xor(q,2); q += __shfl_xor(q,4); q += __shfl_xor(q,8);
      if (lm==0){
        const int row = i*16 + lq*4 + r;
        sred[row*4 + wv] = s;
        sred[BM*4 + row*4 + wv] = q;
      }
    }
  __syncthreads();
  float xv[2][2][4];
  float ps2[2][4], qs2[2][4];
  #pragma unroll
  for (int i=0;i<2;i++)
    #pragma unroll
    for (int r=0;r<4;r++){
      const int row = i*16 + lq*4 + r;
      const float s = sred[row*4+0]+sred[row*4+1]+sred[row*4+2]+sred[row*4+3];
      const float q = sred[BM*4+row*4+0]+sred[BM*4+row*4+1]+sred[BM*4+row*4+2]+sred[BM*4+row*4+3];
      const float mean = s*(1.0f/128.0f);
      const float var  = q*(1.0f/128.0f) - mean*mean;
      const float rstd = rsqrtf(var + 1e-5f);
      float s2 = 0.f, q2 = 0.f;
      #pragma unroll
      for (int j=0;j<2;j++){
        const int col = wn + j*16 + lm;
        const float xnv = (tv[i][j][r]-mean)*rstd*g1[col] + b1[col];
        x_io[(size_t)(m0+row)*EE + col] = xnv;
        xv[i][j][r] = xnv;
        s2 += xnv; q2 += xnv*xnv;
      }
      ps2[i][r] = s2; qs2[i][r] = q2;
    }
  __syncthreads();
  #pragma unroll
  for (int i=0;i<2;i++)
    #pragma unroll
    for (int r=0;r<4;r++){
      float s = ps2[i][r], q = qs2[i][r];
      s += __shfl_xor(s,1); s += __shfl_xor(s,2); s += __shfl_xor(s,4); s += __shfl_xor(s,8);
      q += __shfl_xor(q,1); q += __shfl_xor(q,2); q += __shfl_xor(q,4); q += __shfl_xor(q,8);
      if (lm==0){
        const int row = i*16 + lq*4 + r;
        sred[row*4 + wv] = s;
        sred[BM*4 + row*4 + wv] = q;
      }
    }
  __syncthreads();
  #pragma unroll
  for (int i=0;i<2;i++)
    #pragma unroll
    for (int r=0;r<4;r++){
      const int row = i*16 + lq*4 + r;
      const float s = sred[row*4+0]+sred[row*4+1]+sred[row*4+2]+sred[row*4+3];
      const float q = sred[BM*4+row*4+0]+sred[BM*4+row*4+1]+sred[BM*4+row*4+2]+sred[BM*4+row*4+3];
      const float mean = s*(1.0f/128.0f);
      const float var  = q*(1.0f/128.0f) - mean*mean;
      const float rstd = rsqrtf(var + 1e-5f);
      #pragma unroll
      for (int j=0;j<2;j++){
        const int col = wn + j*16 + lm;
        const float xnv = (xv[i][j][r]-mean)*rstd*g2[col] + b2[col];
        xn_io[(size_t)(m0+row)*EE + col] = f2bf(xnv);
      }
    }
}

// =================== MFMA flash attention (XCD-local grid: bl,h,qt) ===================
// qkc: [tok][h*256 + (q:0..127 | k:128..255)] bf16, tok chunk-local.
// vTc: [h*128+d][tok] bf16 (pre-transposed V), tok chunk-local.
__global__ __launch_bounds__(256) void attn_mf_k(
    const u16* __restrict__ qkc, const u16* __restrict__ vTc,
    const float* __restrict__ w, u16* __restrict__ vals_c, int b0)
{
  const int bl = blockIdx.x;   // id%8 = bl -> one XCD per batch
  const int h  = blockIdx.y;
  const int qt = blockIdx.z;
  const int tid = threadIdx.x;
  const int wv = tid>>6, lane = tid&63;
  const int lm = lane&15, lq = lane>>4;

  __shared__ u16 Qs[64][136];
  __shared__ u16 Ks[64][136];
  __shared__ u16 Vts[128][72];
  __shared__ u16 Ps[64][72];
  __shared__ float wt[64], qwt[64];

  const size_t rs = 2048;
  const u16* qk = qkc + (size_t)bl*SEQ*rs + (size_t)h*256;
  const u16* vb = vTc + (size_t)h*128*CTOK + (size_t)bl*SEQ;
  const int q0 = qt*64;

  #pragma unroll
  for (int it=0; it<4; it++){
    const int fi = it*256 + tid;
    const int r = fi >> 4, g = fi & 15;
    *(float4*)&Qs[r][g*8] = *(const float4*)(qk + (size_t)(q0+r)*rs + g*8);
  }
  if (tid < 64) qwt[tid] = w[(b0+bl)*SEQ + q0 + tid];
  __syncthreads();

  float kq[4];
  #pragma unroll
  for (int r=0;r<4;r++) kq[r] = qwt[wv*16 + lq*4 + r];

  f32x4 oacc[8];
  #pragma unroll
  for (int j=0;j<8;j++) oacc[j] = (f32x4){0.f,0.f,0.f,0.f};
  float mrow[4], lrow[4];
  #pragma unroll
  for (int r=0;r<4;r++){ mrow[r]=-INFINITY; lrow[r]=0.f; }
  const float scale = 0.08838834764831845f;  // 1/sqrt(128)

  for (int kt=0; kt<8; kt++){
    __syncthreads();
    #pragma unroll
    for (int it=0; it<4; it++){
      const int fi = it*256 + tid;
      const int r = fi >> 4, g = fi & 15;
      *(float4*)&Ks[r][g*8] = *(const float4*)(qk + (size_t)(kt*64+r)*rs + 128 + g*8);
    }
    #pragma unroll
    for (int it=0; it<4; it++){
      const int fi = it*256 + tid;
      const int d = fi >> 3, g = fi & 7;
      *(float4*)&Vts[d][g*8] = *(const float4*)(vb + (size_t)d*CTOK + kt*64 + g*8);
    }
    if (tid < 64) wt[tid] = w[(b0+bl)*SEQ + kt*64 + tid];
    __syncthreads();

    f32x4 sacc[4];
    #pragma unroll
    for (int j=0;j<4;j++) sacc[j] = (f32x4){0.f,0.f,0.f,0.f};
    __builtin_amdgcn_s_setprio(1);
    #pragma unroll
    for (int kk=0; kk<4; kk++){
      const bf16x8 af = *(const bf16x8*)&Qs[wv*16+lm][kk*32+lq*8];
      #pragma unroll
      for (int j=0;j<4;j++){
        const bf16x8 bf = *(const bf16x8*)&Ks[j*16+lm][kk*32+lq*8];
        sacc[j] = __builtin_amdgcn_mfma_f32_16x16x32_bf16(af, bf, sacc[j], 0, 0, 0);
      }
    }
    __builtin_amdgcn_s_setprio(0);
    float wkj[4], s[4][4];
    #pragma unroll
    for (int j=0;j<4;j++) wkj[j] = wt[j*16+lm];
    #pragma unroll
    for (int j=0;j<4;j++)
      #pragma unroll
      for (int r=0;r<4;r++){
        const bool keep = (kq[r] > 0.f) && (wkj[j] > 0.f);
        s[j][r] = keep ? sacc[j][r]*scale : -9.0e15f;
      }
    float alpha[4];
    #pragma unroll
    for (int r=0;r<4;r++){
      float rm = fmaxf(fmaxf(s[0][r], s[1][r]), fmaxf(s[2][r], s[3][r]));
      rm = fmaxf(rm, __shfl_xor(rm, 1));
      rm = fmaxf(rm, __shfl_xor(rm, 2));
      rm = fmaxf(rm, __shfl_xor(rm, 4));
      rm = fmaxf(rm, __shfl_xor(rm, 8));
      const float newm = fmaxf(mrow[r], rm);
      alpha[r] = __expf(mrow[r] - newm);
      float ls = 0.f;
      #pragma unroll
      for (int j=0;j<4;j++){
        const float pv = wkj[j]*__expf(s[j][r]-newm);
        s[j][r] = pv; ls += pv;
      }
      ls += __shfl_xor(ls, 1);
      ls += __shfl_xor(ls, 2);
      ls += __shfl_xor(ls, 4);
      ls += __shfl_xor(ls, 8);
      lrow[r] = lrow[r]*alpha[r] + ls;
      mrow[r] = newm;
    }
    // P write/read is wave-local (rows [wv*16, wv*16+16)) -> no barrier;
    // same-wave DS ops execute in order.
    #pragma unroll
    for (int j=0;j<4;j++)
      #pragma unroll
      for (int r=0;r<4;r++)
        Ps[wv*16 + lq*4 + r][j*16+lm] = f2bf(s[j][r]);
    #pragma unroll
    for (int j=0;j<8;j++)
      #pragma unroll
      for (int r=0;r<4;r++) oacc[j][r] *= alpha[r];

    __builtin_amdgcn_s_setprio(1);
    #pragma unroll
    for (int kk=0; kk<2; kk++){
      const bf16x8 pf = *(const bf16x8*)&Ps[wv*16+lm][kk*32+lq*8];
      #pragma unroll
      for (int j=0;j<8;j++){
        const bf16x8 vf = *(const bf16x8*)&Vts[j*16+lm][kk*32+lq*8];
        oacc[j] = __builtin_amdgcn_mfma_f32_16x16x32_bf16(pf, vf, oacc[j], 0, 0, 0);
      }
    }
    __builtin_amdgcn_s_setprio(0);
  }
  #pragma unroll
  for (int r=0;r<4;r++){
    const float inv = 1.0f / lrow[r];
    u16* orow = vals_c + ((size_t)(bl*SEQ + q0 + wv*16 + lq*4 + r))*EHH + h*EE;
    #pragma unroll
    for (int j=0;j<8;j++) orow[j*16+lm] = f2bf(oacc[j][r]*inv);
  }
}

// =================== fused pool: weighted sum + LN + head (4-way split) ===================
__global__ __launch_bounds__(512) void pool_k(
    const float* __restrict__ x, const float* __restrict__ x_init,
    const float* __restrict__ w, const float* __restrict__ g2,
    const float* __restrict__ b2, const float* __restrict__ head_W,
    const float* __restrict__ head_b, float* __restrict__ out)
{
  const int b = blockIdx.x;
  const int tid = threadIdx.x;
  const int e = tid & 127, seg = tid >> 7;
  __shared__ float red[512];
  float acc = 0.f;
  const int n0 = seg*128;
  #pragma unroll 4
  for (int n=n0;n<n0+128;n++){
    const int tok = b*SEQ + n;
    const size_t idx = (size_t)tok*EE + e;
    acc = fmaf(w[tok], x[idx]+x_init[idx], acc);
  }
  red[tid] = acc;
  __syncthreads();
  const float a = (red[e]+red[128+e])+(red[256+e]+red[384+e]);
  __syncthreads();
  if (tid < 128) red[tid] = a;
  __syncthreads();
  for (int s=64;s>0;s>>=1){ if(tid<s) red[tid]+=red[tid+s]; __syncthreads(); }
  const float mean = red[0]*(1.0f/128.0f);
  __syncthreads();
  const float d = a-mean;
  if (tid < 128) red[tid] = d*d;
  __syncthreads();
  for (int s=64;s>0;s>>=1){ if(tid<s) red[tid]+=red[tid+s]; __syncthreads(); }
  const float var = red[0]*(1.0f/128.0f);
  const float p = d*rsqrtf(var+1e-5f)*g2[e]+b2[e];
  __syncthreads();
  if (tid < 128) red[tid] = p*head_W[e];
  __syncthreads();
  for (int s=64;s>0;s>>=1){ if(tid<s) red[tid]+=red[tid+s]; __syncthreads(); }
  if (tid==0) out[b] = red[0] + head_b[0];
}

// =================== launch ===================
extern "C" void kernel_launch(void* const* d_in, const int* in_sizes, int n_in,
                              void* d_out, int out_size, void* d_ws, size_t ws_size,
                              hipStream_t stream)
{
  const float* str_fea   = (const float*)d_in[0];
  const int*   comp_fea  = (const int*)  d_in[1];
  // d_in[2] cell_fea unused by reference
  const float* atom_table= (const float*)d_in[3];
  const float* comp_W    = (const float*)d_in[4];
  const float* comp_b    = (const float*)d_in[5];
  const float* pdd_W     = (const float*)d_in[6];
  const float* pdd_b     = (const float*)d_in[7];
  const float* enc_ln_g  = (const float*)d_in[8];
  const float* enc_ln_b  = (const float*)d_in[9];
  const float* qkv_W     = (const float*)d_in[10];
  const float* qkv_b     = (const float*)d_in[11];
  const float* o_W       = (const float*)d_in[12];
  const float* o_b       = (const float*)d_in[13];
  const float* out_W     = (const float*)d_in[14];
  const float* out_b     = (const float*)d_in[15];
  const float* ffn_W     = (const float*)d_in[16];
  const float* ffn_b     = (const float*)d_in[17];
  const float* ln2_g     = (const float*)d_in[18];
  const float* ln2_b     = (const float*)d_in[19];
  const float* head_W    = (const float*)d_in[20];
  const float* head_b    = (const float*)d_in[21];
  float* out = (float*)d_out;

  // ---- diagnostic 1: input layout model ----
  bool sizes_ok = (n_in >= 22);
  if (sizes_ok){
    sizes_ok = in_sizes[0]==BB*SEQ*KF && in_sizes[1]==NTOK &&
               in_sizes[3]==NATOM*ADIM && in_sizes[4]==ADIM*EE &&
               in_sizes[10]==LL*EE*3*EHH && in_sizes[12]==LL*EHH*EHH &&
               in_sizes[14]==LL*EHH*EE   && in_sizes[16]==LL*EE*EE &&
               in_sizes[20]==EE;
  }
  if (!sizes_ok){
    sentinel_k<<<(out_size+63)/64,64,0,stream>>>(out, 99999.0f, out_size);
    return;
  }

  // ---- workspace layout (~90 MB; <= 109.7 MB proven) ----
  char* p = (char*)d_ws;
  size_t off = 0;
  auto alloc = [&](size_t bytes)->void*{
    off = (off + 255) & ~(size_t)255;
    void* r = p + off; off += bytes; return r;
  };
  float* w        = (float*)alloc((size_t)NTOK*4);
  float* x        = (float*)alloc((size_t)NTOK*EE*4);
  float* x_init   = (float*)alloc((size_t)NTOK*EE*4);
  u16*   xn_bf    = (u16*)  alloc((size_t)NTOK*EE*2);
  u16*   qkc      = (u16*)  alloc((size_t)CTOK*2048*2);   // 16.8 MB chunk (Q|K)
  u16*   vTc      = (u16*)  alloc((size_t)EHH*CTOK*2);    // 8.4 MB chunk (V^T)
  u16*   vals_bf  = (u16*)  alloc((size_t)NTOK*EHH*2);    // 33.6 MB
  u16*   qkvWT_a  = (u16*)  alloc((size_t)LL*3*EHH*EE*2); // 2.36 MB (reordered)
  float* rqkv_b   = (float*)alloc((size_t)LL*3*EHH*4);    // reordered bias
  u16*   fwT_a    = (u16*)  alloc((size_t)LL*EE*EHH*2);   // 0.79 MB
  u16*   ffnWT_a  = (u16*)  alloc((size_t)LL*EE*EE*2);
  u16*   oWb_a    = (u16*)  alloc((size_t)LL*EHH*EHH*2);  // 6.29 MB
  u16*   outWT_a  = (u16*)  alloc((size_t)LL*EE*EHH*2);
  float* fb_a     = (float*)alloc((size_t)LL*EE*4);
  float* atom_emb = (float*)alloc((size_t)NATOM*EE*4);

  // ---- diagnostic 2: workspace size ----
  if (off > ws_size){
    sentinel_k<<<(out_size+63)/64,64,0,stream>>>(out, 12345.0f, out_size);
    return;
  }

  // ---- hoisted weight prep (merged) ----
  prep_k<<<13908,256,0,stream>>>(qkv_W, qkvWT_a, ffn_W, ffnWT_a,
                                 out_W, outWT_a, o_W, oWb_a, qkv_b, rqkv_b);
  fuse_b_k<<<LL,512,0,stream>>>(o_b, out_W, out_b, fb_a);
  // fwT = (o_W @ out_W)^T per layer (EPI4 transposed store), grid.z = layers
  mgemm_k<4,32,64,128><<<dim3(EE/64, EHH/32, LL),256,0,stream>>>(
      oWb_a, outWT_a, nullptr, fwT_a, EE, EHH, EHH, nullptr,
      (size_t)EHH*EHH, (size_t)EE*EHH, (size_t)EE*EHH*2);

  atomemb_k<<<NATOM,256,0,stream>>>(atom_table, comp_W, comp_b, pdd_b, atom_emb);
  embed_ln_k<<<NTOK/64,1024,0,stream>>>(str_fea, comp_fea, atom_emb, pdd_W,
                                        enc_ln_g, enc_ln_b, x, x_init, w, xn_bf);

  for (int i=0;i<LL;i++){
    const float* gi = enc_ln_g + i*EE;
    const float* bi = enc_ln_b + i*EE;
    for (int cb=0; cb<NCHUNK; cb++){
      const int t0 = cb*CTOK;
      const int b0 = cb*CB;
      // QKV with router epilogue: Q|K -> qkc (stride 2048), V -> vTc (transposed)
      mgemm_k<7,128,128,64><<<dim3(3*EHH/128, CTOK/128),256,0,stream>>>(
          xn_bf + (size_t)t0*EE, qkvWT_a + (size_t)i*3*EHH*EE,
          rqkv_b + (size_t)i*3*EHH,
          qkc, 3*EHH, EE, CTOK, vTc, 0, 0, 0);
      attn_mf_k<<<dim3(CB, HH, SEQ/64),256,0,stream>>>(
          qkc, vTc, w, vals_bf + (size_t)t0*EHH, b0);
    }
    // proj + resid + LN + ffn + mish + dual-LN, all in one kernel
    const float* gn = (i<LL-1) ? enc_ln_g + (i+1)*EE : gi;
    const float* bn = (i<LL-1) ? enc_ln_b + (i+1)*EE : bi;
    projffn_k<<<NTOK/32,256,0,stream>>>(
        vals_bf, fwT_a + (size_t)i*EE*EHH, fb_a + (size_t)i*EE,
        ffnWT_a + (size_t)i*EE*EE, ffn_b + (size_t)i*EE,
        gi, bi, gn, bn, x, xn_bf);
  }
  pool_k<<<BB,512,0,stream>>>(x, x_init, w, ln2_g, ln2_b, head_W, head_b, out);
}